// Round 7
// baseline (292.665 us; speedup 1.0000x reference)
//
#include <hip/hip_runtime.h>
#include <math.h>

#define DIM_ 512
#define HID_ 2048
#define B_ 8
#define N_ 1024
#define ROWS_ 8192   // B_*N_
#define TOPK 16      // exact: gate at rank>=16 is <= e^-54 (k<12), contribution ~1e-20

typedef __attribute__((ext_vector_type(8))) short short8;
typedef __attribute__((ext_vector_type(16))) float float16v;
typedef __attribute__((ext_vector_type(4))) float float4v;

__device__ __forceinline__ float sigm(float x) { return 1.f / (1.f + __expf(-x)); }

__device__ __forceinline__ short f2bf(float f) {           // RNE fp32 -> bf16
    unsigned u = __float_as_uint(f);
    u += 0x7FFF + ((u >> 16) & 1);
    return (short)(u >> 16);
}

__device__ __forceinline__ float bf2f(unsigned short s) {
    return __uint_as_float((unsigned)s << 16);
}

// ---- DPP cross-lane reduction helpers (all VALU pipe, zero LDS traffic) ----
// update_dpp ctrl/row_mask must be literal constants -> template parameters.
template<int CTRL>
__device__ __forceinline__ float dpp_fmax_t(float v) {
    const int o = __builtin_amdgcn_update_dpp(__float_as_int(v), __float_as_int(v),
                                              CTRL, 0xF, 0xF, false);  // invalid -> keep v
    return fmaxf(v, __int_as_float(o));
}
// wave-64 max: row_shr 1/2/4/8 then row_bcast15/31; uniform via readlane(63)
__device__ __forceinline__ float wmax64(float v) {
    v = dpp_fmax_t<0x111>(v);   // row_shr:1
    v = dpp_fmax_t<0x112>(v);   // row_shr:2
    v = dpp_fmax_t<0x114>(v);   // row_shr:4
    v = dpp_fmax_t<0x118>(v);   // row_shr:8
    v = dpp_fmax_t<0x142>(v);   // row_bcast:15
    v = dpp_fmax_t<0x143>(v);   // row_bcast:31
    return __int_as_float(__builtin_amdgcn_readlane(__float_as_int(v), 63));
}
template<int CTRL, int RMASK>
__device__ __forceinline__ float dpp_fadd0_t(float v) {
    const int o = __builtin_amdgcn_update_dpp(0, __float_as_int(v), CTRL, RMASK, 0xF, true);
    return v + __int_as_float(o);
}
// wave-64 sum (uniform result via readlane 63)
__device__ __forceinline__ float wsum64(float v) {
    v = dpp_fadd0_t<0x111, 0xF>(v);
    v = dpp_fadd0_t<0x112, 0xF>(v);
    v = dpp_fadd0_t<0x114, 0xF>(v);
    v = dpp_fadd0_t<0x118, 0xF>(v);
    v = dpp_fadd0_t<0x142, 0xA>(v);  // bcast15 into rows 1,3
    v = dpp_fadd0_t<0x143, 0xC>(v);  // bcast31 into rows 2,3
    return __int_as_float(__builtin_amdgcn_readlane(__float_as_int(v), 63));
}
// 16-lane-group butterfly sum, result in ALL lanes of each group:
// xor1/xor2 via quad_perm, xor4 via row_half_mirror, xor8 via row_mirror
template<int CTRL>
__device__ __forceinline__ float qadd_t(float v) {
    const int o = __builtin_amdgcn_update_dpp(__float_as_int(v), __float_as_int(v),
                                              CTRL, 0xF, 0xF, false);
    return v + __int_as_float(o);
}
__device__ __forceinline__ float qsum16(float v) {
    v = qadd_t<0xB1>(v);     // quad_perm [1,0,3,2]  (xor 1)
    v = qadd_t<0x4E>(v);     // quad_perm [2,3,0,1]  (xor 2)
    v = qadd_t<0x141>(v);    // row_half_mirror      (xor 4, quads uniform)
    v = qadd_t<0x140>(v);    // row_mirror           (xor 8, halves uniform)
    return v;
}

__device__ __forceinline__ void gload16(const short* g, short* l) {
    __builtin_amdgcn_global_load_lds(
        (const __attribute__((address_space(1))) void*)g,
        (__attribute__((address_space(3))) void*)l, 16, 0, 0);
}

// ---------------- fused prep: pooled partials + x->bf16  |  weights->bf16 ----------------
__global__ __launch_bounds__(512)
void prep_kernel(const float* __restrict__ x, float* __restrict__ part, short* __restrict__ xb,
                 const float* __restrict__ w1, const float* __restrict__ w2,
                 short* __restrict__ o1, short* __restrict__ o2) {
    const int bx = blockIdx.x;
    if (bx < 256) {
        const int b = bx >> 5, chunk = bx & 31;
        const int cg = (threadIdx.x & 127) * 4;        // channel base (0..508)
        const int rg = threadIdx.x >> 7;               // row-group 0..3 (8 rows each)
        const long long rbase = (long long)b * N_ + chunk * 32 + rg * 8;
        const float* xp = x + rbase * DIM_ + cg;
        short* xo = xb + rbase * DIM_ + cg;
        float4 s = make_float4(0.f, 0.f, 0.f, 0.f);
#pragma unroll
        for (int n = 0; n < 8; ++n) {
            const float4 v = *(const float4*)(xp + (long long)n * DIM_);
            s.x += v.x; s.y += v.y; s.z += v.z; s.w += v.w;
            short4 o;
            o.x = f2bf(v.x); o.y = f2bf(v.y); o.z = f2bf(v.z); o.w = f2bf(v.w);
            *(short4*)(xo + (long long)n * DIM_) = o;
        }
        *(float4*)(part + ((long long)bx * 4 + rg) * DIM_ + cg) = s;
    } else {
        const int n4 = HID_ * DIM_ / 4;                // 262144 float4 per matrix
        int i = (bx - 256) * 2048 + threadIdx.x;
#pragma unroll
        for (int t = 0; t < 4; ++t, i += 512) {
            const float* in = (i < n4) ? w1 : w2;
            short* out = (i < n4) ? o1 : o2;
            const int j = (i < n4) ? i : (i - n4);
            const float4 v = *(const float4*)(in + (long long)j * 4);
            short4 o;
            o.x = f2bf(v.x); o.y = f2bf(v.y); o.z = f2bf(v.z); o.w = f2bf(v.w);
            *(short4*)(out + (long long)j * 4) = o;
        }
    }
}

// ---------------- pooled reduce + head nets (fused): k_cont (B,3), w (B,3) ----------------
__global__ __launch_bounds__(512)
void pool_heads_kernel(const float* __restrict__ part,
                       const float* __restrict__ k1w, const float* __restrict__ k1b,
                       const float* __restrict__ k2w, const float* __restrict__ k2b,
                       const float* __restrict__ w1w, const float* __restrict__ w1b,
                       const float* __restrict__ w2w, const float* __restrict__ w2b,
                       float* __restrict__ kcont, float* __restrict__ wbr) {
    const int b = blockIdx.x;
    const int t = threadIdx.x;                     // 512
    __shared__ float sp[DIM_];
    __shared__ float kh[128], wh[128];
    __shared__ float wraw[4];
    float s = 0.f;
    for (int g = 0; g < 128; ++g) s += part[((long long)b * 128 + g) * DIM_ + t];
    sp[t] = s * (1.f / 1024.f);
    __syncthreads();

    const int wv = t >> 6, l = t & 63;
    float sv[8];
    {
        const float4 a = *(const float4*)&sp[l * 8];
        const float4 c = *(const float4*)&sp[l * 8 + 4];
        sv[0] = a.x; sv[1] = a.y; sv[2] = a.z; sv[3] = a.w;
        sv[4] = c.x; sv[5] = c.y; sv[6] = c.z; sv[7] = c.w;
    }
#pragma unroll 4
    for (int i = 0; i < 16; ++i) {
        const int r = wv * 16 + i;
        const float4 k0 = *(const float4*)(k1w + (long long)r * DIM_ + l * 8);
        const float4 k1 = *(const float4*)(k1w + (long long)r * DIM_ + l * 8 + 4);
        const float4 q0 = *(const float4*)(w1w + (long long)r * DIM_ + l * 8);
        const float4 q1 = *(const float4*)(w1w + (long long)r * DIM_ + l * 8 + 4);
        float ak = sv[0] * k0.x;
        ak = fmaf(sv[1], k0.y, ak); ak = fmaf(sv[2], k0.z, ak); ak = fmaf(sv[3], k0.w, ak);
        ak = fmaf(sv[4], k1.x, ak); ak = fmaf(sv[5], k1.y, ak);
        ak = fmaf(sv[6], k1.z, ak); ak = fmaf(sv[7], k1.w, ak);
        float aw = sv[0] * q0.x;
        aw = fmaf(sv[1], q0.y, aw); aw = fmaf(sv[2], q0.z, aw); aw = fmaf(sv[3], q0.w, aw);
        aw = fmaf(sv[4], q1.x, aw); aw = fmaf(sv[5], q1.y, aw);
        aw = fmaf(sv[6], q1.z, aw); aw = fmaf(sv[7], q1.w, aw);
#pragma unroll
        for (int d = 32; d > 0; d >>= 1) {
            ak += __shfl_xor(ak, d);
            aw += __shfl_xor(aw, d);
        }
        if (l == 0) {
            kh[r] = fmaxf(ak + k1b[r], 0.f);
            wh[r] = fmaxf(aw + w1b[r], 0.f);
        }
    }
    __syncthreads();
    if (t < 3) {
        float rk = k2b[t], rw = w2b[t];
        for (int k = 0; k < 128; ++k) {
            rk = fmaf(kh[k], k2w[t * 128 + k], rk);
            rw = fmaf(wh[k], w2w[t * 128 + k], rw);
        }
        kcont[b * 3 + t] = 1.f + 11.f * sigm(rk);
        wraw[t] = rw;
    }
    __syncthreads();
    if (t == 0) {
        const float m = fmaxf(wraw[0], fmaxf(wraw[1], wraw[2]));
        const float e0 = __expf(wraw[0] - m), e1 = __expf(wraw[1] - m), e2 = __expf(wraw[2] - m);
        const float inv = 1.f / (e0 + e1 + e2);
        wbr[b * 3 + 0] = e0 * inv;
        wbr[b * 3 + 1] = e1 * inv;
        wbr[b * 3 + 2] = e2 * inv;
    }
}

// ---------------- bf16 MFMA NT GEMM, 32x32x16, 128xBN tile (GEMM2 + GEMM3) ----------------
template<int OUTMODE, int BN, int SWZ>
__global__ __launch_bounds__(256)
void gemm_mfma(const short* __restrict__ A, const short* __restrict__ Bm,
               const float* __restrict__ bias,
               float* __restrict__ outF, short* __restrict__ outB,
               int M, int N, int K, int lda, int ldb,
               long long sA, long long sB, long long sC) {
    constexpr int NJ = BN / 64;             // j-frags per wave (2 or 1)
    int bz, mi, ni;
    if (SWZ == 1) {
        const int id = blockIdx.x + gridDim.x * (blockIdx.y + gridDim.y * blockIdx.z);
        bz = id % gridDim.z;
        const int r = id / gridDim.z;
        ni = r % gridDim.x;
        mi = r / gridDim.x;
    } else {
        const int id = blockIdx.x + gridDim.x * blockIdx.y;
        const int numM = gridDim.y;
        const int mg = numM >> 3;           // m-tiles per batch-eighth
        bz = blockIdx.z;
        mi = (id & 7) * mg + (id >> 3) % mg;
        ni = id / numM;
    }
    A  += (long long)bz * sA;
    Bm += (long long)bz * sB;

    __shared__ short As[128 * 64];
    __shared__ short Bs[BN * 64];

    const int tid = threadIdx.x;
    const int lane = tid & 63;
    const int wv = tid >> 6;                // 0..3
    const int m0 = mi * 128;
    const int n0 = ni * BN;

    const int lrow = lane >> 3;             // 0..7
    const int cg = (lane & 7) ^ lrow;       // XOR swizzle

    const int ml = (wv & 1) * 64;
    const int nl = (wv >> 1) * (BN / 2);    // BN=128 -> 64, BN=64 -> 32
    const int fr = lane & 31;               // fragment row/col (m or n)
    const int khh = lane >> 5;              // k-half 0..1

    float16v acc[2][NJ];
#pragma unroll
    for (int i = 0; i < 2; ++i)
#pragma unroll
        for (int j = 0; j < NJ; ++j)
#pragma unroll
            for (int r = 0; r < 16; ++r) acc[i][j][r] = 0.f;

    for (int k0 = 0; k0 < K; k0 += 64) {
        __syncthreads();
#pragma unroll
        for (int i = 0; i < 4; ++i) {
            const int rloc = wv * 32 + i * 8 + lrow;
            gload16(A + (long long)(m0 + rloc) * lda + (k0 + cg * 8),
                    &As[(wv * 32 + i * 8) * 64]);
        }
#pragma unroll
        for (int i = 0; i < BN / 32; ++i) {
            const int rloc = wv * (BN / 4) + i * 8 + lrow;
            gload16(Bm + (long long)(n0 + rloc) * ldb + (k0 + cg * 8),
                    &Bs[(wv * (BN / 4) + i * 8) * 64]);
        }
        __syncthreads();
#pragma unroll
        for (int c = 0; c < 4; ++c) {           // 4 ksteps of K=16
            const int ch = c * 2 + khh;         // 8-elem chunk index
            short8 af[2], bfr[NJ];
#pragma unroll
            for (int i = 0; i < 2; ++i) {
                const int m = ml + i * 32 + fr;
                af[i] = *(const short8*)&As[m * 64 + ((ch ^ (m & 7)) * 8)];
            }
#pragma unroll
            for (int j = 0; j < NJ; ++j) {
                const int n = nl + j * 32 + fr;
                bfr[j] = *(const short8*)&Bs[n * 64 + ((ch ^ (n & 7)) * 8)];
            }
#pragma unroll
            for (int i = 0; i < 2; ++i)
#pragma unroll
                for (int j = 0; j < NJ; ++j)
                    acc[i][j] = __builtin_amdgcn_mfma_f32_32x32x16_bf16(
                        af[i], bfr[j], acc[i][j], 0, 0, 0);
        }
    }

    const long long outOfs = (long long)bz * sC;
#pragma unroll
    for (int i = 0; i < 2; ++i) {
#pragma unroll
        for (int j = 0; j < NJ; ++j) {
            const int ng = n0 + nl + j * 32 + fr;
            float bv = 0.f;
            if (OUTMODE != 2) bv = bias[ng];
#pragma unroll
            for (int r = 0; r < 16; ++r) {
                const int mg2 = m0 + ml + i * 32 + (r & 3) + 8 * (r >> 2) + 4 * khh;
                float v = acc[i][j][r] + bv;
                if (OUTMODE == 0) v = fmaxf(v, 0.f);
                const long long idx = outOfs + (long long)mg2 * N + ng;
                if (OUTMODE == 2) outF[idx] = v;
                else              outB[idx] = f2bf(v);
            }
        }
    }
}

// ---------------- bf16 MFMA NT GEMM, 256x256 8-phase deep-pipelined (GEMM1) -------
// 8 waves (2M x 4N), per-wave 128x64 out, MFMA 16x16x32, BK=64, LDS 128 KiB dbuf.
// Counted vmcnt {6,6,-,4} steady, epilogue {2,0,-,-}; never vmcnt(0) in main loop.
template<int OUTMODE, bool BATCH>
__global__ __launch_bounds__(512, 2)
void gemm256(const short* __restrict__ A, const short* __restrict__ Bm,
             const float* __restrict__ bias, float* __restrict__ outF,
             short* __restrict__ outB, int M, int N, int K, int lda, int ldb,
             int mTiles, long long sA, long long sB, long long sC) {
    __shared__ short As[2][256 * 64];
    __shared__ short Bs[2][256 * 64];

    const int tid = threadIdx.x;
    const int lane = tid & 63;
    const int wv = tid >> 6;           // 0..7
    const int l15 = lane & 15;
    const int kq = lane >> 4;          // 0..3
    const int lr = lane >> 3;          // 0..7 stripe-row
    const int cg = (lane & 7) ^ lr;    // pre-swizzled source chunk

    const int id = blockIdx.x;
    const int xcd = id & 7;            // batch / m-group -> XCD pinned
    const int r = id >> 3;
    int mi, ni;
    const short* Ag = A;
    const short* Bg = Bm;
    long long cOfs = 0;
    if (BATCH) {
        mi = r % mTiles; ni = r / mTiles;
        Ag += (long long)xcd * sA; Bg += (long long)xcd * sB; cOfs = (long long)xcd * sC;
    } else {
        const int mg = mTiles >> 3;    // m-tiles per XCD chunk
        mi = xcd * mg + r % mg; ni = r / mg;
    }
    const int m0 = mi * 256, n0 = ni * 256;
    const int wm = wv >> 2, wn = wv & 3;

    float4v acc[8][4];
#pragma unroll
    for (int i = 0; i < 8; ++i)
#pragma unroll
        for (int j = 0; j < 4; ++j)
#pragma unroll
            for (int q = 0; q < 4; ++q) acc[i][j][q] = 0.f;

    const int sB1 = (wv & 3) + (wv >> 2) * 8;

    auto stA = [&](int bf, int s, int k0) {
        gload16(Ag + (long long)(m0 + s * 8 + lr) * lda + (k0 + cg * 8), &As[bf][s * 8 * 64]);
    };
    auto stB = [&](int bf, int s, int k0) {
        gload16(Bg + (long long)(n0 + s * 8 + lr) * ldb + (k0 + cg * 8), &Bs[bf][s * 8 * 64]);
    };
    auto unit0 = [&](int bf, int k0) {
        stA(bf, wv, k0); stA(bf, 16 + wv, k0);
        stB(bf, sB1, k0); stB(bf, 16 + sB1, k0);
    };
    auto unit1 = [&](int bf, int k0) { stA(bf, 8 + wv, k0); stA(bf, 24 + wv, k0); };
    auto unit2 = [&](int bf, int k0) { stB(bf, 4 + sB1, k0); stB(bf, 20 + sB1, k0); };

    auto tile_body = [&](int bf, int k1, bool stage) {
#pragma unroll
        for (int p = 0; p < 4; ++p) {
            const int mq = p & 1, nq = p >> 1;
            short8 af[4][2], bfr[2][2];
#pragma unroll
            for (int f = 0; f < 4; ++f) {
                const int rA = wm * 128 + mq * 64 + f * 16 + l15;
                const int ro = rA * 64, sw = rA & 7;
#pragma unroll
                for (int ks = 0; ks < 2; ++ks)
                    af[f][ks] = *(const short8*)&As[bf][ro + (((ks * 4 + kq) ^ sw) * 8)];
            }
#pragma unroll
            for (int g = 0; g < 2; ++g) {
                const int rB = wn * 64 + nq * 32 + g * 16 + l15;
                const int ro = rB * 64, sw = rB & 7;
#pragma unroll
                for (int ks = 0; ks < 2; ++ks)
                    bfr[g][ks] = *(const short8*)&Bs[bf][ro + (((ks * 4 + kq) ^ sw) * 8)];
            }
            if (stage) {
                if (p == 0) unit0(bf ^ 1, k1);
                else if (p == 1) unit1(bf ^ 1, k1);
                else if (p == 2) unit2(bf ^ 1, k1);
                if (p == 0 || p == 1) asm volatile("s_waitcnt vmcnt(6)" ::: "memory");
                else if (p == 3)      asm volatile("s_waitcnt vmcnt(4)" ::: "memory");
            } else {
                if (p == 0)      asm volatile("s_waitcnt vmcnt(2)" ::: "memory");
                else if (p == 1) asm volatile("s_waitcnt vmcnt(0)" ::: "memory");
            }
            __builtin_amdgcn_s_barrier();
            asm volatile("s_waitcnt lgkmcnt(0)" ::: "memory");
            __builtin_amdgcn_sched_barrier(0);          // rule #18: pin MFMA after the wait
            __builtin_amdgcn_s_setprio(1);
#pragma unroll
            for (int f = 0; f < 4; ++f)
#pragma unroll
                for (int g = 0; g < 2; ++g)
#pragma unroll
                    for (int ks = 0; ks < 2; ++ks)
                        acc[mq * 4 + f][nq * 2 + g] = __builtin_amdgcn_mfma_f32_16x16x32_bf16(
                            af[f][ks], bfr[g][ks], acc[mq * 4 + f][nq * 2 + g], 0, 0, 0);
            __builtin_amdgcn_s_setprio(0);
            if (stage || p < 3) __builtin_amdgcn_s_barrier();
        }
    };

    const int NT = K >> 6;             // >= 2 for all uses here
    // prologue: stage tile 0 fully (unit order fixed for vmcnt accounting)
    unit0(0, 0);
    __builtin_amdgcn_sched_barrier(0);
    unit1(0, 0);
    __builtin_amdgcn_sched_barrier(0);
    unit2(0, 0);
    asm volatile("s_waitcnt vmcnt(4)" ::: "memory");   // U0 landed; U1,U2 in flight
    __builtin_amdgcn_s_barrier();

    for (int t = 0; t < NT - 1; ++t)
        tile_body(t & 1, (t + 1) << 6, true);
    tile_body((NT - 1) & 1, 0, false);                 // epilogue tile, drains 2->0

    // C-write: col = lane&15, row = (lane>>4)*4 + reg
#pragma unroll
    for (int mf = 0; mf < 8; ++mf) {
#pragma unroll
        for (int nf = 0; nf < 4; ++nf) {
            const int ng = n0 + wn * 64 + nf * 16 + l15;
            float bv = 0.f;
            if (OUTMODE != 2) bv = bias[ng];
            const int mb = m0 + wm * 128 + mf * 16 + kq * 4;
#pragma unroll
            for (int q = 0; q < 4; ++q) {
                float v = acc[mf][nf][q] + bv;
                if (OUTMODE == 0) v = fmaxf(v, 0.f);
                const long long idx = cOfs + (long long)(mb + q) * N + ng;
                if (OUTMODE == 2) outF[idx] = v;
                else              outB[idx] = f2bf(v);
            }
        }
    }
}

// ---------------- fused per-row top-16 + aggregate, ONE row per wave ----------------
// v6: iterative wave-max EXTRACTION, exact fp32, zero LDS-pipe traffic:
//   per-lane sort of 16 (value,idx) pairs -> 16 rounds of {DPP wave-max (7 VALU),
//   ballot+ffs owner (lowest lane = lowest idx block = reference stable tie-break),
//   readlane owner's head idx, owner pops}. Denominator + group sums via DPP
//   row_shr/bcast and quad_perm/mirror butterflies. No 22-bit screen, no phase B.
__global__ __launch_bounds__(256)
void topk_agg_kernel(const float* __restrict__ sim,
                     const float* __restrict__ kcont, const float* __restrict__ wbr,
                     const unsigned short* __restrict__ h, float* __restrict__ y) {
    const int wv = threadIdx.x >> 6;
    const int lane = threadIdx.x & 63;
    const int ll = lane & 15;
    const int id = blockIdx.x;                    // 2048
    const int b = id & 7;                         // batch -> XCD pinned
    const int row = b * N_ + (id >> 3) * 4 + wv;  // 1024 rows per batch
    const float* srow = sim + (long long)row * N_;

    const int base = lane * 16;
    float f[16];
#pragma unroll
    for (int q = 0; q < 4; ++q) {
        const float4 v = *(const float4*)(srow + base + q * 4);
        f[q * 4 + 0] = v.x; f[q * 4 + 1] = v.y; f[q * 4 + 2] = v.z; f[q * 4 + 3] = v.w;
    }

    // row max: lane-local then DPP wave max (no LDS)
    float lm = f[0];
#pragma unroll
    for (int j = 1; j < 16; ++j) lm = fmaxf(lm, f[j]);
    const float maxv = wmax64(lm);

    // softmax denominator: 16 exps + DPP wave sum
    float so = 0.f;
#pragma unroll
    for (int j = 0; j < 16; ++j) so += __expf(f[j] - maxv);
    const float invden = 1.f / wsum64(so);

    // ---- per-lane sort of (value, idx) pairs, descending by value ----
    float sv[16];
    int   si[16];
#pragma unroll
    for (int j = 0; j < 16; ++j) { sv[j] = f[j]; si[j] = base + j; }
#pragma unroll
    for (int k = 2; k <= 16; k <<= 1) {
#pragma unroll
        for (int jj = k >> 1; jj > 0; jj >>= 1) {
#pragma unroll
            for (int i = 0; i < 16; ++i) {
                const int l = i ^ jj;
                if (l > i) {
                    const bool desc = ((i & k) == 0);
                    const bool sw = desc ? (sv[i] < sv[l]) : (sv[i] > sv[l]);
                    const float tv = sw ? sv[l] : sv[i];
                    sv[l] = sw ? sv[i] : sv[l];
                    sv[i] = tv;
                    const int ti = sw ? si[l] : si[i];
                    si[l] = sw ? si[i] : si[l];
                    si[i] = ti;
                }
            }
        }
    }

    // ---- 16 rounds of wave-max extraction; lane r (mod 16) records rank r ----
    float rv = -3.0e38f;
    int   ri = 0;
#pragma unroll
    for (int r = 0; r < TOPK; ++r) {
        const float gm = wmax64(sv[0]);
        const unsigned long long bal = __ballot(sv[0] == gm);
        const int owner = __ffsll(bal) - 1;
        const int oidx = __builtin_amdgcn_readlane(si[0], owner);
        if (ll == r) { rv = gm; ri = oidx; }      // all 4 groups record (cndmask)
        if (lane == owner) {                       // owner pops its sorted head
#pragma unroll
            for (int j = 0; j < 15; ++j) { sv[j] = sv[j + 1]; si[j] = si[j + 1]; }
            sv[15] = -3.0e38f;
        }
    }

    const float kc0 = kcont[b * 3 + 0], kc1 = kcont[b * 3 + 1], kc2 = kcont[b * 3 + 2];
    const float w0 = wbr[b * 3 + 0], w1 = wbr[b * 3 + 1], w2 = wbr[b * 3 + 2];

    const float p = __expf(rv - maxv) * invden;   // lanes with rv=-inf -> p=0
    const float rr = (float)ll + 0.5f;
    const float g0 = sigm(12.f * (kc0 - rr));
    const float g1 = sigm(12.f * (kc1 - rr));
    const float g2 = sigm(12.f * (kc2 - rr));
    // 16-lane-group sums via DPP butterfly (all lanes get result)
    const float s0 = qsum16(p * g0);
    const float s1 = qsum16(p * g1);
    const float s2 = qsum16(p * g2);
    const float f0 = w0 / (s0 + 1e-8f);
    const float f1 = w1 / (s1 + 1e-8f);
    const float f2 = w2 / (s2 + 1e-8f);
    const float mycoef = p * (f0 * g0 + f1 * g1 + f2 * g2);

    // gather: 16 coalesced 1KB rows; rank-r coef/idx via v_readlane from lane r
    const unsigned short* hbase = h + (long long)b * (N_ * DIM_) + lane * 8;
    float acc[8] = {0.f, 0.f, 0.f, 0.f, 0.f, 0.f, 0.f, 0.f};
#pragma unroll
    for (int r = 0; r < TOPK; ++r) {
        const float c = __uint_as_float(
            (unsigned)__builtin_amdgcn_readlane((int)__float_as_uint(mycoef), r));
        const int   i = __builtin_amdgcn_readlane(ri, r);
        const ushort4 a0 = *(const ushort4*)(hbase + (long long)i * DIM_);
        const ushort4 a1 = *(const ushort4*)(hbase + (long long)i * DIM_ + 4);
        acc[0] = fmaf(c, bf2f(a0.x), acc[0]);
        acc[1] = fmaf(c, bf2f(a0.y), acc[1]);
        acc[2] = fmaf(c, bf2f(a0.z), acc[2]);
        acc[3] = fmaf(c, bf2f(a0.w), acc[3]);
        acc[4] = fmaf(c, bf2f(a1.x), acc[4]);
        acc[5] = fmaf(c, bf2f(a1.y), acc[5]);
        acc[6] = fmaf(c, bf2f(a1.z), acc[6]);
        acc[7] = fmaf(c, bf2f(a1.w), acc[7]);
    }
    float* yp = y + (long long)row * DIM_ + lane * 8;
    *(float4*)(yp + 0) = make_float4(acc[0], acc[1], acc[2], acc[3]);
    *(float4*)(yp + 4) = make_float4(acc[4], acc[5], acc[6], acc[7]);
}

extern "C" void kernel_launch(void* const* d_in, const int* in_sizes, int n_in,
                              void* d_out, int out_size, void* d_ws, size_t ws_size,
                              hipStream_t stream) {
    const float* x     = (const float*)d_in[0];
    const float* fc1_w = (const float*)d_in[1];
    const float* fc1_b = (const float*)d_in[2];
    const float* fc2_w = (const float*)d_in[3];
    const float* fc2_b = (const float*)d_in[4];
    const float* k1_w  = (const float*)d_in[5];
    const float* k1_b  = (const float*)d_in[6];
    const float* k2_w  = (const float*)d_in[7];
    const float* k2_b  = (const float*)d_in[8];
    const float* w1_w  = (const float*)d_in[9];
    const float* w1_b  = (const float*)d_in[10];
    const float* w2_w  = (const float*)d_in[11];
    const float* w2_b  = (const float*)d_in[12];

    char* ws = (char*)d_ws;
    short* h1b    = (short*)(ws + 0);              // 33,554,432 (live fc1->fc2)
    float* simbuf = (float*)(ws + 0);              // 33,554,432 (reuse after fc2)
    short* xb     = (short*)(ws + 33554432);       // 8,388,608
    short* hb     = (short*)(ws + 67108864);       // 8,388,608
    short* w1b    = (short*)(ws + 75497472);       // 2,097,152
    short* w2b    = (short*)(ws + 77594624);       // 2,097,152
    float* ppart  = (float*)(ws + 79691776);       // 2,097,152 (256 blocks x 4 rowgroups x 512)
    float* kcont  = (float*)(ws + 81788928);       // 128
    float* wbr    = (float*)(ws + 81789056);       // 128

    float* y = (float*)d_out;

    // 0) fused prep: pooled partials + x->bf16 (blocks 0..255), weights->bf16 (256..511)
    prep_kernel<<<dim3(512), dim3(512), 0, stream>>>(x, ppart, xb, fc1_w, fc2_w, w1b, w2b);
    // 1) pooled reduce + head nets (wave-parallel matvec)
    pool_heads_kernel<<<dim3(B_), dim3(512), 0, stream>>>(ppart, k1_w, k1_b, k2_w, k2_b,
                                                          w1_w, w1_b, w2_w, w2_b, kcont, wbr);
    // 2) h1 = relu(x @ fc1_w^T + b1) -> bf16   M=8192 N=2048 K=512
    //    256x256 8-phase: 32x8 = 256 blocks, 1/CU, m-tiles XCD-pinned
    gemm256<0, false><<<dim3(256), dim3(512), 0, stream>>>(
        xb, w1b, fc1_b, nullptr, h1b, ROWS_, HID_, DIM_, DIM_, DIM_, 32, 0, 0, 0);
    // 3) h = h1 @ fc2_w^T + b2 -> bf16 direct  M=8192 N=512 K=2048 (128x64, batch-pinned m)
    gemm_mfma<1, 64, 2><<<dim3(DIM_ / 64, ROWS_ / 128, 1), dim3(256), 0, stream>>>(
        h1b, w2b, fc2_b, nullptr, hb, ROWS_, DIM_, HID_, HID_, HID_, 0, 0, 0);
    // 4) sim[b] = hb[b] @ hb[b]^T -> fp32      M=N=1024 K=512, batch 8 (batch-XCD pinned)
    gemm_mfma<2, 128, 1><<<dim3(N_ / 128, N_ / 128, B_), dim3(256), 0, stream>>>(
        hb, hb, nullptr, simbuf, nullptr, N_, N_, DIM_, DIM_, DIM_,
        (long long)N_ * DIM_, (long long)N_ * DIM_, (long long)N_ * N_);
    // 5) fused per-row top-16 + aggregate (1 row/wave, DPP extraction, zero LDS)
    topk_agg_kernel<<<dim3(ROWS_ / 4), dim3(256), 0, stream>>>(
        simbuf, kcont, wbr, (const unsigned short*)hb, y);
}

// Round 8
// 214.906 us; speedup vs baseline: 1.3618x; 1.3618x over previous
//
#include <hip/hip_runtime.h>
#include <math.h>

#define DIM_ 512
#define HID_ 2048
#define B_ 8
#define N_ 1024
#define ROWS_ 8192   // B_*N_
#define TOPK 16      // exact: gate at rank>=16 is <= e^-54 (k<12), contribution ~1e-20

typedef __attribute__((ext_vector_type(8))) short short8;
typedef __attribute__((ext_vector_type(16))) float float16v;
typedef __attribute__((ext_vector_type(4))) float float4v;

__device__ __forceinline__ float sigm(float x) { return 1.f / (1.f + __expf(-x)); }

__device__ __forceinline__ short f2bf(float f) {           // RNE fp32 -> bf16
    unsigned u = __float_as_uint(f);
    u += 0x7FFF + ((u >> 16) & 1);
    return (short)(u >> 16);
}

__device__ __forceinline__ float bf2f(unsigned short s) {
    return __uint_as_float((unsigned)s << 16);
}

__device__ __forceinline__ unsigned f2ord(float f) {       // monotone fp32 -> u32
    unsigned u = __float_as_uint(f);
    return (u & 0x80000000u) ? ~u : (u | 0x80000000u);
}

// ---- cross-lane helpers: xor1/xor2 on the VALU pipe (DPP quad_perm), rest LDS pipe ----
__device__ __forceinline__ unsigned dpp_xor1(unsigned v) {  // quad_perm [1,0,3,2]
    return (unsigned)__builtin_amdgcn_update_dpp(0, (int)v, 0xB1, 0xF, 0xF, true);
}
__device__ __forceinline__ unsigned dpp_xor2(unsigned v) {  // quad_perm [2,3,0,1]
    return (unsigned)__builtin_amdgcn_update_dpp(0, (int)v, 0x4E, 0xF, 0xF, true);
}
__device__ __forceinline__ unsigned sxr(unsigned v, int d) { // d folds to const after unroll
    if (d == 1) return dpp_xor1(v);
    if (d == 2) return dpp_xor2(v);
    return (unsigned)__shfl_xor((int)v, d);
}
__device__ __forceinline__ float sxrf(float v, int d) {
    return __uint_as_float(sxr(__float_as_uint(v), d));
}

__device__ __forceinline__ void gload16(const short* g, short* l) {
    __builtin_amdgcn_global_load_lds(
        (const __attribute__((address_space(1))) void*)g,
        (__attribute__((address_space(3))) void*)l, 16, 0, 0);
}

// ---------------- fused prep: pooled partials + x->bf16  |  weights->bf16 ----------------
__global__ __launch_bounds__(512)
void prep_kernel(const float* __restrict__ x, float* __restrict__ part, short* __restrict__ xb,
                 const float* __restrict__ w1, const float* __restrict__ w2,
                 short* __restrict__ o1, short* __restrict__ o2) {
    const int bx = blockIdx.x;
    if (bx < 256) {
        const int b = bx >> 5, chunk = bx & 31;
        const int cg = (threadIdx.x & 127) * 4;        // channel base (0..508)
        const int rg = threadIdx.x >> 7;               // row-group 0..3 (8 rows each)
        const long long rbase = (long long)b * N_ + chunk * 32 + rg * 8;
        const float* xp = x + rbase * DIM_ + cg;
        short* xo = xb + rbase * DIM_ + cg;
        float4 s = make_float4(0.f, 0.f, 0.f, 0.f);
#pragma unroll
        for (int n = 0; n < 8; ++n) {
            const float4 v = *(const float4*)(xp + (long long)n * DIM_);
            s.x += v.x; s.y += v.y; s.z += v.z; s.w += v.w;
            short4 o;
            o.x = f2bf(v.x); o.y = f2bf(v.y); o.z = f2bf(v.z); o.w = f2bf(v.w);
            *(short4*)(xo + (long long)n * DIM_) = o;
        }
        *(float4*)(part + ((long long)bx * 4 + rg) * DIM_ + cg) = s;
    } else {
        const int n4 = HID_ * DIM_ / 4;                // 262144 float4 per matrix
        int i = (bx - 256) * 2048 + threadIdx.x;
#pragma unroll
        for (int t = 0; t < 4; ++t, i += 512) {
            const float* in = (i < n4) ? w1 : w2;
            short* out = (i < n4) ? o1 : o2;
            const int j = (i < n4) ? i : (i - n4);
            const float4 v = *(const float4*)(in + (long long)j * 4);
            short4 o;
            o.x = f2bf(v.x); o.y = f2bf(v.y); o.z = f2bf(v.z); o.w = f2bf(v.w);
            *(short4*)(out + (long long)j * 4) = o;
        }
    }
}

// ---------------- pooled reduce + head nets (fused): k_cont (B,3), w (B,3) ----------------
__global__ __launch_bounds__(512)
void pool_heads_kernel(const float* __restrict__ part,
                       const float* __restrict__ k1w, const float* __restrict__ k1b,
                       const float* __restrict__ k2w, const float* __restrict__ k2b,
                       const float* __restrict__ w1w, const float* __restrict__ w1b,
                       const float* __restrict__ w2w, const float* __restrict__ w2b,
                       float* __restrict__ kcont, float* __restrict__ wbr) {
    const int b = blockIdx.x;
    const int t = threadIdx.x;                     // 512
    __shared__ float sp[DIM_];
    __shared__ float kh[128], wh[128];
    __shared__ float wraw[4];
    float s = 0.f;
    for (int g = 0; g < 128; ++g) s += part[((long long)b * 128 + g) * DIM_ + t];
    sp[t] = s * (1.f / 1024.f);
    __syncthreads();

    const int wv = t >> 6, l = t & 63;
    float sv[8];
    {
        const float4 a = *(const float4*)&sp[l * 8];
        const float4 c = *(const float4*)&sp[l * 8 + 4];
        sv[0] = a.x; sv[1] = a.y; sv[2] = a.z; sv[3] = a.w;
        sv[4] = c.x; sv[5] = c.y; sv[6] = c.z; sv[7] = c.w;
    }
#pragma unroll 4
    for (int i = 0; i < 16; ++i) {
        const int r = wv * 16 + i;
        const float4 k0 = *(const float4*)(k1w + (long long)r * DIM_ + l * 8);
        const float4 k1 = *(const float4*)(k1w + (long long)r * DIM_ + l * 8 + 4);
        const float4 q0 = *(const float4*)(w1w + (long long)r * DIM_ + l * 8);
        const float4 q1 = *(const float4*)(w1w + (long long)r * DIM_ + l * 8 + 4);
        float ak = sv[0] * k0.x;
        ak = fmaf(sv[1], k0.y, ak); ak = fmaf(sv[2], k0.z, ak); ak = fmaf(sv[3], k0.w, ak);
        ak = fmaf(sv[4], k1.x, ak); ak = fmaf(sv[5], k1.y, ak);
        ak = fmaf(sv[6], k1.z, ak); ak = fmaf(sv[7], k1.w, ak);
        float aw = sv[0] * q0.x;
        aw = fmaf(sv[1], q0.y, aw); aw = fmaf(sv[2], q0.z, aw); aw = fmaf(sv[3], q0.w, aw);
        aw = fmaf(sv[4], q1.x, aw); aw = fmaf(sv[5], q1.y, aw);
        aw = fmaf(sv[6], q1.z, aw); aw = fmaf(sv[7], q1.w, aw);
#pragma unroll
        for (int d = 32; d > 0; d >>= 1) {
            ak += __shfl_xor(ak, d);
            aw += __shfl_xor(aw, d);
        }
        if (l == 0) {
            kh[r] = fmaxf(ak + k1b[r], 0.f);
            wh[r] = fmaxf(aw + w1b[r], 0.f);
        }
    }
    __syncthreads();
    if (t < 3) {
        float rk = k2b[t], rw = w2b[t];
        for (int k = 0; k < 128; ++k) {
            rk = fmaf(kh[k], k2w[t * 128 + k], rk);
            rw = fmaf(wh[k], w2w[t * 128 + k], rw);
        }
        kcont[b * 3 + t] = 1.f + 11.f * sigm(rk);
        wraw[t] = rw;
    }
    __syncthreads();
    if (t == 0) {
        const float m = fmaxf(wraw[0], fmaxf(wraw[1], wraw[2]));
        const float e0 = __expf(wraw[0] - m), e1 = __expf(wraw[1] - m), e2 = __expf(wraw[2] - m);
        const float inv = 1.f / (e0 + e1 + e2);
        wbr[b * 3 + 0] = e0 * inv;
        wbr[b * 3 + 1] = e1 * inv;
        wbr[b * 3 + 2] = e2 * inv;
    }
}

// ---------------- bf16 MFMA NT GEMM, 32x32x16, 128xBN tile (GEMM2 + GEMM3) ----------------
template<int OUTMODE, int BN, int SWZ>
__global__ __launch_bounds__(256)
void gemm_mfma(const short* __restrict__ A, const short* __restrict__ Bm,
               const float* __restrict__ bias,
               float* __restrict__ outF, short* __restrict__ outB,
               int M, int N, int K, int lda, int ldb,
               long long sA, long long sB, long long sC) {
    constexpr int NJ = BN / 64;             // j-frags per wave (2 or 1)
    int bz, mi, ni;
    if (SWZ == 1) {
        const int id = blockIdx.x + gridDim.x * (blockIdx.y + gridDim.y * blockIdx.z);
        bz = id % gridDim.z;
        const int r = id / gridDim.z;
        ni = r % gridDim.x;
        mi = r / gridDim.x;
    } else {
        const int id = blockIdx.x + gridDim.x * blockIdx.y;
        const int numM = gridDim.y;
        const int mg = numM >> 3;           // m-tiles per batch-eighth
        bz = blockIdx.z;
        mi = (id & 7) * mg + (id >> 3) % mg;
        ni = id / numM;
    }
    A  += (long long)bz * sA;
    Bm += (long long)bz * sB;

    __shared__ short As[128 * 64];
    __shared__ short Bs[BN * 64];

    const int tid = threadIdx.x;
    const int lane = tid & 63;
    const int wv = tid >> 6;                // 0..3
    const int m0 = mi * 128;
    const int n0 = ni * BN;

    const int lrow = lane >> 3;             // 0..7
    const int cg = (lane & 7) ^ lrow;       // XOR swizzle

    const int ml = (wv & 1) * 64;
    const int nl = (wv >> 1) * (BN / 2);    // BN=128 -> 64, BN=64 -> 32
    const int fr = lane & 31;               // fragment row/col (m or n)
    const int khh = lane >> 5;              // k-half 0..1

    float16v acc[2][NJ];
#pragma unroll
    for (int i = 0; i < 2; ++i)
#pragma unroll
        for (int j = 0; j < NJ; ++j)
#pragma unroll
            for (int r = 0; r < 16; ++r) acc[i][j][r] = 0.f;

    for (int k0 = 0; k0 < K; k0 += 64) {
        __syncthreads();
#pragma unroll
        for (int i = 0; i < 4; ++i) {
            const int rloc = wv * 32 + i * 8 + lrow;
            gload16(A + (long long)(m0 + rloc) * lda + (k0 + cg * 8),
                    &As[(wv * 32 + i * 8) * 64]);
        }
#pragma unroll
        for (int i = 0; i < BN / 32; ++i) {
            const int rloc = wv * (BN / 4) + i * 8 + lrow;
            gload16(Bm + (long long)(n0 + rloc) * ldb + (k0 + cg * 8),
                    &Bs[(wv * (BN / 4) + i * 8) * 64]);
        }
        __syncthreads();
#pragma unroll
        for (int c = 0; c < 4; ++c) {           // 4 ksteps of K=16
            const int ch = c * 2 + khh;         // 8-elem chunk index
            short8 af[2], bfr[NJ];
#pragma unroll
            for (int i = 0; i < 2; ++i) {
                const int m = ml + i * 32 + fr;
                af[i] = *(const short8*)&As[m * 64 + ((ch ^ (m & 7)) * 8)];
            }
#pragma unroll
            for (int j = 0; j < NJ; ++j) {
                const int n = nl + j * 32 + fr;
                bfr[j] = *(const short8*)&Bs[n * 64 + ((ch ^ (n & 7)) * 8)];
            }
#pragma unroll
            for (int i = 0; i < 2; ++i)
#pragma unroll
                for (int j = 0; j < NJ; ++j)
                    acc[i][j] = __builtin_amdgcn_mfma_f32_32x32x16_bf16(
                        af[i], bfr[j], acc[i][j], 0, 0, 0);
        }
    }

    const long long outOfs = (long long)bz * sC;
#pragma unroll
    for (int i = 0; i < 2; ++i) {
#pragma unroll
        for (int j = 0; j < NJ; ++j) {
            const int ng = n0 + nl + j * 32 + fr;
            float bv = 0.f;
            if (OUTMODE != 2) bv = bias[ng];
#pragma unroll
            for (int r = 0; r < 16; ++r) {
                const int mg2 = m0 + ml + i * 32 + (r & 3) + 8 * (r >> 2) + 4 * khh;
                float v = acc[i][j][r] + bv;
                if (OUTMODE == 0) v = fmaxf(v, 0.f);
                const long long idx = outOfs + (long long)mg2 * N + ng;
                if (OUTMODE == 2) outF[idx] = v;
                else              outB[idx] = f2bf(v);
            }
        }
    }
}

// ---------------- bf16 MFMA NT GEMM, 256x256 8-phase deep-pipelined (GEMM1) -------
// 8 waves (2M x 4N), per-wave 128x64 out, MFMA 16x16x32, BK=64, LDS 128 KiB dbuf.
// Counted vmcnt {6,6,-,4} steady, epilogue {2,0,-,-}; never vmcnt(0) in main loop.
template<int OUTMODE, bool BATCH>
__global__ __launch_bounds__(512, 2)
void gemm256(const short* __restrict__ A, const short* __restrict__ Bm,
             const float* __restrict__ bias, float* __restrict__ outF,
             short* __restrict__ outB, int M, int N, int K, int lda, int ldb,
             int mTiles, long long sA, long long sB, long long sC) {
    __shared__ short As[2][256 * 64];
    __shared__ short Bs[2][256 * 64];

    const int tid = threadIdx.x;
    const int lane = tid & 63;
    const int wv = tid >> 6;           // 0..7
    const int l15 = lane & 15;
    const int kq = lane >> 4;          // 0..3
    const int lr = lane >> 3;          // 0..7 stripe-row
    const int cg = (lane & 7) ^ lr;    // pre-swizzled source chunk

    const int id = blockIdx.x;
    const int xcd = id & 7;            // batch / m-group -> XCD pinned
    const int r = id >> 3;
    int mi, ni;
    const short* Ag = A;
    const short* Bg = Bm;
    long long cOfs = 0;
    if (BATCH) {
        mi = r % mTiles; ni = r / mTiles;
        Ag += (long long)xcd * sA; Bg += (long long)xcd * sB; cOfs = (long long)xcd * sC;
    } else {
        const int mg = mTiles >> 3;    // m-tiles per XCD chunk
        mi = xcd * mg + r % mg; ni = r / mg;
    }
    const int m0 = mi * 256, n0 = ni * 256;
    const int wm = wv >> 2, wn = wv & 3;

    float4v acc[8][4];
#pragma unroll
    for (int i = 0; i < 8; ++i)
#pragma unroll
        for (int j = 0; j < 4; ++j)
#pragma unroll
            for (int q = 0; q < 4; ++q) acc[i][j][q] = 0.f;

    const int sB1 = (wv & 3) + (wv >> 2) * 8;

    auto stA = [&](int bf, int s, int k0) {
        gload16(Ag + (long long)(m0 + s * 8 + lr) * lda + (k0 + cg * 8), &As[bf][s * 8 * 64]);
    };
    auto stB = [&](int bf, int s, int k0) {
        gload16(Bg + (long long)(n0 + s * 8 + lr) * ldb + (k0 + cg * 8), &Bs[bf][s * 8 * 64]);
    };
    auto unit0 = [&](int bf, int k0) {
        stA(bf, wv, k0); stA(bf, 16 + wv, k0);
        stB(bf, sB1, k0); stB(bf, 16 + sB1, k0);
    };
    auto unit1 = [&](int bf, int k0) { stA(bf, 8 + wv, k0); stA(bf, 24 + wv, k0); };
    auto unit2 = [&](int bf, int k0) { stB(bf, 4 + sB1, k0); stB(bf, 20 + sB1, k0); };

    auto tile_body = [&](int bf, int k1, bool stage) {
#pragma unroll
        for (int p = 0; p < 4; ++p) {
            const int mq = p & 1, nq = p >> 1;
            short8 af[4][2], bfr[2][2];
#pragma unroll
            for (int f = 0; f < 4; ++f) {
                const int rA = wm * 128 + mq * 64 + f * 16 + l15;
                const int ro = rA * 64, sw = rA & 7;
#pragma unroll
                for (int ks = 0; ks < 2; ++ks)
                    af[f][ks] = *(const short8*)&As[bf][ro + (((ks * 4 + kq) ^ sw) * 8)];
            }
#pragma unroll
            for (int g = 0; g < 2; ++g) {
                const int rB = wn * 64 + nq * 32 + g * 16 + l15;
                const int ro = rB * 64, sw = rB & 7;
#pragma unroll
                for (int ks = 0; ks < 2; ++ks)
                    bfr[g][ks] = *(const short8*)&Bs[bf][ro + (((ks * 4 + kq) ^ sw) * 8)];
            }
            if (stage) {
                if (p == 0) unit0(bf ^ 1, k1);
                else if (p == 1) unit1(bf ^ 1, k1);
                else if (p == 2) unit2(bf ^ 1, k1);
                if (p == 0 || p == 1) asm volatile("s_waitcnt vmcnt(6)" ::: "memory");
                else if (p == 3)      asm volatile("s_waitcnt vmcnt(4)" ::: "memory");
            } else {
                if (p == 0)      asm volatile("s_waitcnt vmcnt(2)" ::: "memory");
                else if (p == 1) asm volatile("s_waitcnt vmcnt(0)" ::: "memory");
            }
            __builtin_amdgcn_s_barrier();
            asm volatile("s_waitcnt lgkmcnt(0)" ::: "memory");
            __builtin_amdgcn_sched_barrier(0);          // rule #18: pin MFMA after the wait
            __builtin_amdgcn_s_setprio(1);
#pragma unroll
            for (int f = 0; f < 4; ++f)
#pragma unroll
                for (int g = 0; g < 2; ++g)
#pragma unroll
                    for (int ks = 0; ks < 2; ++ks)
                        acc[mq * 4 + f][nq * 2 + g] = __builtin_amdgcn_mfma_f32_16x16x32_bf16(
                            af[f][ks], bfr[g][ks], acc[mq * 4 + f][nq * 2 + g], 0, 0, 0);
            __builtin_amdgcn_s_setprio(0);
            if (stage || p < 3) __builtin_amdgcn_s_barrier();
        }
    };

    const int NT = K >> 6;             // >= 2 for all uses here
    // prologue: stage tile 0 fully (unit order fixed for vmcnt accounting)
    unit0(0, 0);
    __builtin_amdgcn_sched_barrier(0);
    unit1(0, 0);
    __builtin_amdgcn_sched_barrier(0);
    unit2(0, 0);
    asm volatile("s_waitcnt vmcnt(4)" ::: "memory");   // U0 landed; U1,U2 in flight
    __builtin_amdgcn_s_barrier();

    for (int t = 0; t < NT - 1; ++t)
        tile_body(t & 1, (t + 1) << 6, true);
    tile_body((NT - 1) & 1, 0, false);                 // epilogue tile, drains 2->0

    // C-write: col = lane&15, row = (lane>>4)*4 + reg
#pragma unroll
    for (int mf = 0; mf < 8; ++mf) {
#pragma unroll
        for (int nf = 0; nf < 4; ++nf) {
            const int ng = n0 + wn * 64 + nf * 16 + l15;
            float bv = 0.f;
            if (OUTMODE != 2) bv = bias[ng];
            const int mb = m0 + wm * 128 + mf * 16 + kq * 4;
#pragma unroll
            for (int q = 0; q < 4; ++q) {
                float v = acc[mf][nf][q] + bv;
                if (OUTMODE == 0) v = fmaxf(v, 0.f);
                const long long idx = cOfs + (long long)(mb + q) * N + ng;
                if (OUTMODE == 2) outF[idx] = v;
                else              outB[idx] = f2bf(v);
            }
        }
    }
}

// ---------------- fused per-row top-16 + aggregate, ONE row per wave (R5 revert) ----------
// R7's extraction variant spilled its register arrays (VGPR=36 < needed ~50) -> scratch
// -> 113 us. This is the proven R5 structure: 22-bit-key bitonic sort + 6 merge rounds
// (xor1/2 on DPP), exact fp32 re-rank in 16-lane groups, readlane gather. ~40 us.
__global__ __launch_bounds__(256)
void topk_agg_kernel(const float* __restrict__ sim,
                     const float* __restrict__ kcont, const float* __restrict__ wbr,
                     const unsigned short* __restrict__ h, float* __restrict__ y) {
    const int wv = threadIdx.x >> 6;
    const int lane = threadIdx.x & 63;
    const int ll = lane & 15;
    const int id = blockIdx.x;                    // 2048
    const int b = id & 7;                         // batch -> XCD pinned
    const int row = b * N_ + (id >> 3) * 4 + wv;  // 1024 rows per batch
    const float* srow = sim + (long long)row * N_;

    const int base = lane * 16;
    float f[16];
#pragma unroll
    for (int q = 0; q < 4; ++q) {
        const float4 v = *(const float4*)(srow + base + q * 4);
        f[q * 4 + 0] = v.x; f[q * 4 + 1] = v.y; f[q * 4 + 2] = v.z; f[q * 4 + 3] = v.w;
    }

    // row max
    float m = f[0];
#pragma unroll
    for (int j = 1; j < 16; ++j) m = fmaxf(m, f[j]);
#pragma unroll
    for (int d = 32; d > 0; d >>= 1) m = fmaxf(m, sxrf(m, d));
    const float maxv = m;

    // softmax denominator
    float so = 0.f;
#pragma unroll
    for (int j = 0; j < 16; ++j) so += __expf(f[j] - maxv);
#pragma unroll
    for (int d = 32; d > 0; d >>= 1) so += sxrf(so, d);
    const float invden = 1.f / so;

    // ---- Phase A: u32 keys (top-22 float bits | index), lane-local bitonic sort desc ----
    unsigned key[16];
#pragma unroll
    for (int j = 0; j < 16; ++j)
        key[j] = (f2ord(f[j]) & 0xFFFFFC00u) | (unsigned)(1023 - (base + j));

#pragma unroll
    for (int k = 2; k <= 16; k <<= 1) {
#pragma unroll
        for (int j = k >> 1; j > 0; j >>= 1) {
#pragma unroll
            for (int i = 0; i < 16; ++i) {
                const int l = i ^ j;
                if (l > i) {
                    const bool desc = ((i & k) == 0);
                    const unsigned a = key[i], bk = key[l];
                    const unsigned hi = (a > bk) ? a : bk;
                    const unsigned lo = (a > bk) ? bk : a;
                    key[i] = desc ? hi : lo;
                    key[l] = desc ? lo : hi;
                }
            }
        }
    }

    // 6 merge rounds -> every lane holds global sorted top-16 (desc) in key[0..15]
#pragma unroll
    for (int d = 1; d < 64; d <<= 1) {
        unsigned o[16];
#pragma unroll
        for (int i = 0; i < 16; ++i) o[i] = sxr(key[15 - i], d);
#pragma unroll
        for (int i = 0; i < 16; ++i) key[i] = (key[i] > o[i]) ? key[i] : o[i];
#pragma unroll
        for (int j = 8; j > 0; j >>= 1) {
#pragma unroll
            for (int i = 0; i < 16; ++i) {
                if ((i & j) == 0) {
                    const unsigned a = key[i], bk = key[i | j];
                    key[i]     = (a > bk) ? a : bk;
                    key[i | j] = (a > bk) ? bk : a;
                }
            }
        }
    }

    // ---- Phase B: 4 identical 16-lane groups resolve exact fp32 order of top-16 ----
    unsigned k32 = 0;
#pragma unroll
    for (int j = 0; j < 16; ++j) k32 = (ll == j) ? key[j] : k32;
    const int myidx = 1023 - (int)(k32 & 1023u);
    const float myval = srow[myidx];                 // L1-hot exact fp32

    unsigned long long kx = ((unsigned long long)f2ord(myval) << 32)
                          | (unsigned)(1023 - myidx);
#pragma unroll
    for (int k = 2; k <= 16; k <<= 1) {
#pragma unroll
        for (int d = k >> 1; d > 0; d >>= 1) {       // d<=8: stays in 16-lane group
            const unsigned olo = sxr((unsigned)kx, d);
            const unsigned ohi = sxr((unsigned)(kx >> 32), d);
            const unsigned long long other = ((unsigned long long)ohi << 32) | olo;
            const bool keepMax = (((ll & k) != 0) == ((ll & d) != 0));
            const bool mineBig = (kx > other);
            kx = (keepMax == mineBig) ? kx : other;
        }
    }
    const unsigned sord = (unsigned)(kx >> 32);
    const unsigned su = (sord & 0x80000000u) ? (sord & 0x7FFFFFFFu) : ~sord;
    const float sval = __uint_as_float(su);
    const int sidx = 1023 - (int)(kx & 1023u);

    const float kc0 = kcont[b * 3 + 0], kc1 = kcont[b * 3 + 1], kc2 = kcont[b * 3 + 2];
    const float w0 = wbr[b * 3 + 0], w1 = wbr[b * 3 + 1], w2 = wbr[b * 3 + 2];

    const float p = __expf(sval - maxv) * invden;
    const float rr = (float)ll + 0.5f;
    const float g0 = sigm(12.f * (kc0 - rr));
    const float g1 = sigm(12.f * (kc1 - rr));
    const float g2 = sigm(12.f * (kc2 - rr));
    float s0 = p * g0, s1 = p * g1, s2 = p * g2;
#pragma unroll
    for (int d = 1; d < 16; d <<= 1) {
        s0 += sxrf(s0, d);
        s1 += sxrf(s1, d);
        s2 += sxrf(s2, d);
    }
    const float f0 = w0 / (s0 + 1e-8f);
    const float f1 = w1 / (s1 + 1e-8f);
    const float f2 = w2 / (s2 + 1e-8f);
    const float mycoef = p * (f0 * g0 + f1 * g1 + f2 * g2);

    // gather: 16 coalesced 1KB rows; rank-r coef/idx via v_readlane from lane r
    const unsigned short* hbase = h + (long long)b * (N_ * DIM_) + lane * 8;
    float acc[8] = {0.f, 0.f, 0.f, 0.f, 0.f, 0.f, 0.f, 0.f};
#pragma unroll
    for (int r = 0; r < TOPK; ++r) {
        const float c = __uint_as_float(
            (unsigned)__builtin_amdgcn_readlane((int)__float_as_uint(mycoef), r));
        const int   i = __builtin_amdgcn_readlane(sidx, r);
        const ushort4 a0 = *(const ushort4*)(hbase + (long long)i * DIM_);
        const ushort4 a1 = *(const ushort4*)(hbase + (long long)i * DIM_ + 4);
        acc[0] = fmaf(c, bf2f(a0.x), acc[0]);
        acc[1] = fmaf(c, bf2f(a0.y), acc[1]);
        acc[2] = fmaf(c, bf2f(a0.z), acc[2]);
        acc[3] = fmaf(c, bf2f(a0.w), acc[3]);
        acc[4] = fmaf(c, bf2f(a1.x), acc[4]);
        acc[5] = fmaf(c, bf2f(a1.y), acc[5]);
        acc[6] = fmaf(c, bf2f(a1.z), acc[6]);
        acc[7] = fmaf(c, bf2f(a1.w), acc[7]);
    }
    float* yp = y + (long long)row * DIM_ + lane * 8;
    *(float4*)(yp + 0) = make_float4(acc[0], acc[1], acc[2], acc[3]);
    *(float4*)(yp + 4) = make_float4(acc[4], acc[5], acc[6], acc[7]);
}

extern "C" void kernel_launch(void* const* d_in, const int* in_sizes, int n_in,
                              void* d_out, int out_size, void* d_ws, size_t ws_size,
                              hipStream_t stream) {
    const float* x     = (const float*)d_in[0];
    const float* fc1_w = (const float*)d_in[1];
    const float* fc1_b = (const float*)d_in[2];
    const float* fc2_w = (const float*)d_in[3];
    const float* fc2_b = (const float*)d_in[4];
    const float* k1_w  = (const float*)d_in[5];
    const float* k1_b  = (const float*)d_in[6];
    const float* k2_w  = (const float*)d_in[7];
    const float* k2_b  = (const float*)d_in[8];
    const float* w1_w  = (const float*)d_in[9];
    const float* w1_b  = (const float*)d_in[10];
    const float* w2_w  = (const float*)d_in[11];
    const float* w2_b  = (const float*)d_in[12];

    char* ws = (char*)d_ws;
    short* h1b    = (short*)(ws + 0);              // 33,554,432 (live fc1->fc2)
    float* simbuf = (float*)(ws + 0);              // 33,554,432 (reuse after fc2)
    short* xb     = (short*)(ws + 33554432);       // 8,388,608
    short* hb     = (short*)(ws + 67108864);       // 8,388,608
    short* w1b    = (short*)(ws + 75497472);       // 2,097,152
    short* w2b    = (short*)(ws + 77594624);       // 2,097,152
    float* ppart  = (float*)(ws + 79691776);       // 2,097,152 (256 blocks x 4 rowgroups x 512)
    float* kcont  = (float*)(ws + 81788928);       // 128
    float* wbr    = (float*)(ws + 81789056);       // 128

    float* y = (float*)d_out;

    // 0) fused prep: pooled partials + x->bf16 (blocks 0..255), weights->bf16 (256..511)
    prep_kernel<<<dim3(512), dim3(512), 0, stream>>>(x, ppart, xb, fc1_w, fc2_w, w1b, w2b);
    // 1) pooled reduce + head nets (wave-parallel matvec)
    pool_heads_kernel<<<dim3(B_), dim3(512), 0, stream>>>(ppart, k1_w, k1_b, k2_w, k2_b,
                                                          w1_w, w1_b, w2_w, w2_b, kcont, wbr);
    // 2) h1 = relu(x @ fc1_w^T + b1) -> bf16   M=8192 N=2048 K=512
    //    256x256 8-phase: 32x8 = 256 blocks, 1/CU, m-tiles XCD-pinned
    gemm256<0, false><<<dim3(256), dim3(512), 0, stream>>>(
        xb, w1b, fc1_b, nullptr, h1b, ROWS_, HID_, DIM_, DIM_, DIM_, 32, 0, 0, 0);
    // 3) h = h1 @ fc2_w^T + b2 -> bf16 direct  M=8192 N=512 K=2048
    //    BN 64->128: 128x128 tiles, 4x64 grid = 256 blocks (1/CU), A-panel streamed 4x not 8x
    gemm_mfma<1, 128, 2><<<dim3(DIM_ / 128, ROWS_ / 128, 1), dim3(256), 0, stream>>>(
        h1b, w2b, fc2_b, nullptr, hb, ROWS_, DIM_, HID_, HID_, HID_, 0, 0, 0);
    // 4) sim[b] = hb[b] @ hb[b]^T -> fp32      M=N=1024 K=512, batch 8 (batch-XCD pinned)
    gemm_mfma<2, 128, 1><<<dim3(N_ / 128, N_ / 128, B_), dim3(256), 0, stream>>>(
        hb, hb, nullptr, simbuf, nullptr, N_, N_, DIM_, DIM_, DIM_,
        (long long)N_ * DIM_, (long long)N_ * DIM_, (long long)N_ * N_);
    // 5) fused per-row top-16 + aggregate (1 row/wave, R5-proven structure)
    topk_agg_kernel<<<dim3(ROWS_ / 4), dim3(256), 0, stream>>>(
        simbuf, kcont, wbr, (const unsigned short*)hb, y);
}

// Round 9
// 210.917 us; speedup vs baseline: 1.3876x; 1.0189x over previous
//
#include <hip/hip_runtime.h>
#include <math.h>

#define DIM_ 512
#define HID_ 2048
#define B_ 8
#define N_ 1024
#define ROWS_ 8192   // B_*N_
#define TOPK 16      // exact: gate at rank>=16 is <= e^-54 (k<12), contribution ~1e-20

typedef __attribute__((ext_vector_type(8))) short short8;
typedef __attribute__((ext_vector_type(16))) float float16v;

__device__ __forceinline__ float sigm(float x) { return 1.f / (1.f + __expf(-x)); }

__device__ __forceinline__ short f2bf(float f) {           // RNE fp32 -> bf16
    unsigned u = __float_as_uint(f);
    u += 0x7FFF + ((u >> 16) & 1);
    return (short)(u >> 16);
}

__device__ __forceinline__ float bf2f(unsigned short s) {
    return __uint_as_float((unsigned)s << 16);
}

__device__ __forceinline__ unsigned f2ord(float f) {       // monotone fp32 -> u32
    unsigned u = __float_as_uint(f);
    return (u & 0x80000000u) ? ~u : (u | 0x80000000u);
}

// ---- cross-lane helpers: xor1/xor2 on the VALU pipe (DPP quad_perm), rest LDS pipe ----
__device__ __forceinline__ unsigned dpp_xor1(unsigned v) {  // quad_perm [1,0,3,2]
    return (unsigned)__builtin_amdgcn_update_dpp(0, (int)v, 0xB1, 0xF, 0xF, true);
}
__device__ __forceinline__ unsigned dpp_xor2(unsigned v) {  // quad_perm [2,3,0,1]
    return (unsigned)__builtin_amdgcn_update_dpp(0, (int)v, 0x4E, 0xF, 0xF, true);
}
__device__ __forceinline__ unsigned sxr(unsigned v, int d) { // d folds to const after unroll
    if (d == 1) return dpp_xor1(v);
    if (d == 2) return dpp_xor2(v);
    return (unsigned)__shfl_xor((int)v, d);
}
__device__ __forceinline__ float sxrf(float v, int d) {
    return __uint_as_float(sxr(__float_as_uint(v), d));
}

__device__ __forceinline__ void gload16(const short* g, short* l) {
    __builtin_amdgcn_global_load_lds(
        (const __attribute__((address_space(1))) void*)g,
        (__attribute__((address_space(3))) void*)l, 16, 0, 0);
}

// ---------------- fused prep: pooled partials + x->bf16  |  weights->bf16 ----------------
__global__ __launch_bounds__(512)
void prep_kernel(const float* __restrict__ x, float* __restrict__ part, short* __restrict__ xb,
                 const float* __restrict__ w1, const float* __restrict__ w2,
                 short* __restrict__ o1, short* __restrict__ o2) {
    const int bx = blockIdx.x;
    if (bx < 256) {
        const int b = bx >> 5, chunk = bx & 31;
        const int cg = (threadIdx.x & 127) * 4;        // channel base (0..508)
        const int rg = threadIdx.x >> 7;               // row-group 0..3 (8 rows each)
        const long long rbase = (long long)b * N_ + chunk * 32 + rg * 8;
        const float* xp = x + rbase * DIM_ + cg;
        short* xo = xb + rbase * DIM_ + cg;
        float4 s = make_float4(0.f, 0.f, 0.f, 0.f);
#pragma unroll
        for (int n = 0; n < 8; ++n) {
            const float4 v = *(const float4*)(xp + (long long)n * DIM_);
            s.x += v.x; s.y += v.y; s.z += v.z; s.w += v.w;
            short4 o;
            o.x = f2bf(v.x); o.y = f2bf(v.y); o.z = f2bf(v.z); o.w = f2bf(v.w);
            *(short4*)(xo + (long long)n * DIM_) = o;
        }
        *(float4*)(part + ((long long)bx * 4 + rg) * DIM_ + cg) = s;
    } else {
        const int n4 = HID_ * DIM_ / 4;                // 262144 float4 per matrix
        int i = (bx - 256) * 2048 + threadIdx.x;
#pragma unroll
        for (int t = 0; t < 4; ++t, i += 512) {
            const float* in = (i < n4) ? w1 : w2;
            short* out = (i < n4) ? o1 : o2;
            const int j = (i < n4) ? i : (i - n4);
            const float4 v = *(const float4*)(in + (long long)j * 4);
            short4 o;
            o.x = f2bf(v.x); o.y = f2bf(v.y); o.z = f2bf(v.z); o.w = f2bf(v.w);
            *(short4*)(out + (long long)j * 4) = o;
        }
    }
}

// ---------------- pooled reduce + head nets (fused): k_cont (B,3), w (B,3) ----------------
__global__ __launch_bounds__(512)
void pool_heads_kernel(const float* __restrict__ part,
                       const float* __restrict__ k1w, const float* __restrict__ k1b,
                       const float* __restrict__ k2w, const float* __restrict__ k2b,
                       const float* __restrict__ w1w, const float* __restrict__ w1b,
                       const float* __restrict__ w2w, const float* __restrict__ w2b,
                       float* __restrict__ kcont, float* __restrict__ wbr) {
    const int b = blockIdx.x;
    const int t = threadIdx.x;                     // 512
    __shared__ float sp[DIM_];
    __shared__ float kh[128], wh[128];
    __shared__ float wraw[4];
    float s = 0.f;
    for (int g = 0; g < 128; ++g) s += part[((long long)b * 128 + g) * DIM_ + t];
    sp[t] = s * (1.f / 1024.f);
    __syncthreads();

    const int wv = t >> 6, l = t & 63;
    float sv[8];
    {
        const float4 a = *(const float4*)&sp[l * 8];
        const float4 c = *(const float4*)&sp[l * 8 + 4];
        sv[0] = a.x; sv[1] = a.y; sv[2] = a.z; sv[3] = a.w;
        sv[4] = c.x; sv[5] = c.y; sv[6] = c.z; sv[7] = c.w;
    }
#pragma unroll 4
    for (int i = 0; i < 16; ++i) {
        const int r = wv * 16 + i;
        const float4 k0 = *(const float4*)(k1w + (long long)r * DIM_ + l * 8);
        const float4 k1 = *(const float4*)(k1w + (long long)r * DIM_ + l * 8 + 4);
        const float4 q0 = *(const float4*)(w1w + (long long)r * DIM_ + l * 8);
        const float4 q1 = *(const float4*)(w1w + (long long)r * DIM_ + l * 8 + 4);
        float ak = sv[0] * k0.x;
        ak = fmaf(sv[1], k0.y, ak); ak = fmaf(sv[2], k0.z, ak); ak = fmaf(sv[3], k0.w, ak);
        ak = fmaf(sv[4], k1.x, ak); ak = fmaf(sv[5], k1.y, ak);
        ak = fmaf(sv[6], k1.z, ak); ak = fmaf(sv[7], k1.w, ak);
        float aw = sv[0] * q0.x;
        aw = fmaf(sv[1], q0.y, aw); aw = fmaf(sv[2], q0.z, aw); aw = fmaf(sv[3], q0.w, aw);
        aw = fmaf(sv[4], q1.x, aw); aw = fmaf(sv[5], q1.y, aw);
        aw = fmaf(sv[6], q1.z, aw); aw = fmaf(sv[7], q1.w, aw);
#pragma unroll
        for (int d = 32; d > 0; d >>= 1) {
            ak += __shfl_xor(ak, d);
            aw += __shfl_xor(aw, d);
        }
        if (l == 0) {
            kh[r] = fmaxf(ak + k1b[r], 0.f);
            wh[r] = fmaxf(aw + w1b[r], 0.f);
        }
    }
    __syncthreads();
    if (t < 3) {
        float rk = k2b[t], rw = w2b[t];
        for (int k = 0; k < 128; ++k) {
            rk = fmaf(kh[k], k2w[t * 128 + k], rk);
            rw = fmaf(wh[k], w2w[t * 128 + k], rw);
        }
        kcont[b * 3 + t] = 1.f + 11.f * sigm(rk);
        wraw[t] = rw;
    }
    __syncthreads();
    if (t == 0) {
        const float m = fmaxf(wraw[0], fmaxf(wraw[1], wraw[2]));
        const float e0 = __expf(wraw[0] - m), e1 = __expf(wraw[1] - m), e2 = __expf(wraw[2] - m);
        const float inv = 1.f / (e0 + e1 + e2);
        wbr[b * 3 + 0] = e0 * inv;
        wbr[b * 3 + 1] = e1 * inv;
        wbr[b * 3 + 2] = e2 * inv;
    }
}

// ---------------- bf16 MFMA NT GEMM, 32x32x16, 128xBN tile (all three GEMMs) ----------------
// R8 lesson: the 2-barrier structure needs >=2 blocks/CU for implicit drain overlap (m114);
// BN=64 for G2 (512 blocks) beats BN=128 (256 blocks, 1/CU, +5us).
template<int OUTMODE, int BN, int SWZ>
__global__ __launch_bounds__(256)
void gemm_mfma(const short* __restrict__ A, const short* __restrict__ Bm,
               const float* __restrict__ bias,
               float* __restrict__ outF, short* __restrict__ outB,
               int M, int N, int K, int lda, int ldb,
               long long sA, long long sB, long long sC) {
    constexpr int NJ = BN / 64;             // j-frags per wave (2 or 1)
    int bz, mi, ni;
    if (SWZ == 1) {
        const int id = blockIdx.x + gridDim.x * (blockIdx.y + gridDim.y * blockIdx.z);
        bz = id % gridDim.z;
        const int r = id / gridDim.z;
        ni = r % gridDim.x;
        mi = r / gridDim.x;
    } else {
        const int id = blockIdx.x + gridDim.x * blockIdx.y;
        const int numM = gridDim.y;
        const int mg = numM >> 3;           // m-tiles per batch-eighth
        bz = blockIdx.z;
        mi = (id & 7) * mg + (id >> 3) % mg;
        ni = id / numM;
    }
    A  += (long long)bz * sA;
    Bm += (long long)bz * sB;

    __shared__ short As[128 * 64];
    __shared__ short Bs[BN * 64];

    const int tid = threadIdx.x;
    const int lane = tid & 63;
    const int wv = tid >> 6;                // 0..3
    const int m0 = mi * 128;
    const int n0 = ni * BN;

    const int lrow = lane >> 3;             // 0..7
    const int cg = (lane & 7) ^ lrow;       // XOR swizzle

    const int ml = (wv & 1) * 64;
    const int nl = (wv >> 1) * (BN / 2);    // BN=128 -> 64, BN=64 -> 32
    const int fr = lane & 31;               // fragment row/col (m or n)
    const int khh = lane >> 5;              // k-half 0..1

    float16v acc[2][NJ];
#pragma unroll
    for (int i = 0; i < 2; ++i)
#pragma unroll
        for (int j = 0; j < NJ; ++j)
#pragma unroll
            for (int r = 0; r < 16; ++r) acc[i][j][r] = 0.f;

    for (int k0 = 0; k0 < K; k0 += 64) {
        __syncthreads();
#pragma unroll
        for (int i = 0; i < 4; ++i) {
            const int rloc = wv * 32 + i * 8 + lrow;
            gload16(A + (long long)(m0 + rloc) * lda + (k0 + cg * 8),
                    &As[(wv * 32 + i * 8) * 64]);
        }
#pragma unroll
        for (int i = 0; i < BN / 32; ++i) {
            const int rloc = wv * (BN / 4) + i * 8 + lrow;
            gload16(Bm + (long long)(n0 + rloc) * ldb + (k0 + cg * 8),
                    &Bs[(wv * (BN / 4) + i * 8) * 64]);
        }
        __syncthreads();
#pragma unroll
        for (int c = 0; c < 4; ++c) {           // 4 ksteps of K=16
            const int ch = c * 2 + khh;         // 8-elem chunk index
            short8 af[2], bfr[NJ];
#pragma unroll
            for (int i = 0; i < 2; ++i) {
                const int m = ml + i * 32 + fr;
                af[i] = *(const short8*)&As[m * 64 + ((ch ^ (m & 7)) * 8)];
            }
#pragma unroll
            for (int j = 0; j < NJ; ++j) {
                const int n = nl + j * 32 + fr;
                bfr[j] = *(const short8*)&Bs[n * 64 + ((ch ^ (n & 7)) * 8)];
            }
#pragma unroll
            for (int i = 0; i < 2; ++i)
#pragma unroll
                for (int j = 0; j < NJ; ++j)
                    acc[i][j] = __builtin_amdgcn_mfma_f32_32x32x16_bf16(
                        af[i], bfr[j], acc[i][j], 0, 0, 0);
        }
    }

    const long long outOfs = (long long)bz * sC;
#pragma unroll
    for (int i = 0; i < 2; ++i) {
#pragma unroll
        for (int j = 0; j < NJ; ++j) {
            const int ng = n0 + nl + j * 32 + fr;
            float bv = 0.f;
            if (OUTMODE != 2) bv = bias[ng];
#pragma unroll
            for (int r = 0; r < 16; ++r) {
                const int mg2 = m0 + ml + i * 32 + (r & 3) + 8 * (r >> 2) + 4 * khh;
                float v = acc[i][j][r] + bv;
                if (OUTMODE == 0) v = fmaxf(v, 0.f);
                const long long idx = outOfs + (long long)mg2 * N + ng;
                if (OUTMODE == 2) outF[idx] = v;
                else              outB[idx] = f2bf(v);
            }
        }
    }
}

// ---------------- fused per-row top-16 + aggregate, ONE row per wave (R5-proven) ----------
// 22-bit-key bitonic sort + 6 merge rounds (xor1/2 on DPP), exact fp32 re-rank in
// 16-lane groups, readlane gather. VGPR=48, no spill.
__global__ __launch_bounds__(256)
void topk_agg_kernel(const float* __restrict__ sim,
                     const float* __restrict__ kcont, const float* __restrict__ wbr,
                     const unsigned short* __restrict__ h, float* __restrict__ y) {
    const int wv = threadIdx.x >> 6;
    const int lane = threadIdx.x & 63;
    const int ll = lane & 15;
    const int id = blockIdx.x;                    // 2048
    const int b = id & 7;                         // batch -> XCD pinned
    const int row = b * N_ + (id >> 3) * 4 + wv;  // 1024 rows per batch
    const float* srow = sim + (long long)row * N_;

    const int base = lane * 16;
    float f[16];
#pragma unroll
    for (int q = 0; q < 4; ++q) {
        const float4 v = *(const float4*)(srow + base + q * 4);
        f[q * 4 + 0] = v.x; f[q * 4 + 1] = v.y; f[q * 4 + 2] = v.z; f[q * 4 + 3] = v.w;
    }

    // row max
    float m = f[0];
#pragma unroll
    for (int j = 1; j < 16; ++j) m = fmaxf(m, f[j]);
#pragma unroll
    for (int d = 32; d > 0; d >>= 1) m = fmaxf(m, sxrf(m, d));
    const float maxv = m;

    // softmax denominator
    float so = 0.f;
#pragma unroll
    for (int j = 0; j < 16; ++j) so += __expf(f[j] - maxv);
#pragma unroll
    for (int d = 32; d > 0; d >>= 1) so += sxrf(so, d);
    const float invden = 1.f / so;

    // ---- Phase A: u32 keys (top-22 float bits | index), lane-local bitonic sort desc ----
    unsigned key[16];
#pragma unroll
    for (int j = 0; j < 16; ++j)
        key[j] = (f2ord(f[j]) & 0xFFFFFC00u) | (unsigned)(1023 - (base + j));

#pragma unroll
    for (int k = 2; k <= 16; k <<= 1) {
#pragma unroll
        for (int j = k >> 1; j > 0; j >>= 1) {
#pragma unroll
            for (int i = 0; i < 16; ++i) {
                const int l = i ^ j;
                if (l > i) {
                    const bool desc = ((i & k) == 0);
                    const unsigned a = key[i], bk = key[l];
                    const unsigned hi = (a > bk) ? a : bk;
                    const unsigned lo = (a > bk) ? bk : a;
                    key[i] = desc ? hi : lo;
                    key[l] = desc ? lo : hi;
                }
            }
        }
    }

    // 6 merge rounds -> every lane holds global sorted top-16 (desc) in key[0..15]
#pragma unroll
    for (int d = 1; d < 64; d <<= 1) {
        unsigned o[16];
#pragma unroll
        for (int i = 0; i < 16; ++i) o[i] = sxr(key[15 - i], d);
#pragma unroll
        for (int i = 0; i < 16; ++i) key[i] = (key[i] > o[i]) ? key[i] : o[i];
#pragma unroll
        for (int j = 8; j > 0; j >>= 1) {
#pragma unroll
            for (int i = 0; i < 16; ++i) {
                if ((i & j) == 0) {
                    const unsigned a = key[i], bk = key[i | j];
                    key[i]     = (a > bk) ? a : bk;
                    key[i | j] = (a > bk) ? bk : a;
                }
            }
        }
    }

    // ---- Phase B: 4 identical 16-lane groups resolve exact fp32 order of top-16 ----
    unsigned k32 = 0;
#pragma unroll
    for (int j = 0; j < 16; ++j) k32 = (ll == j) ? key[j] : k32;
    const int myidx = 1023 - (int)(k32 & 1023u);
    const float myval = srow[myidx];                 // L1-hot exact fp32

    unsigned long long kx = ((unsigned long long)f2ord(myval) << 32)
                          | (unsigned)(1023 - myidx);
#pragma unroll
    for (int k = 2; k <= 16; k <<= 1) {
#pragma unroll
        for (int d = k >> 1; d > 0; d >>= 1) {       // d<=8: stays in 16-lane group
            const unsigned olo = sxr((unsigned)kx, d);
            const unsigned ohi = sxr((unsigned)(kx >> 32), d);
            const unsigned long long other = ((unsigned long long)ohi << 32) | olo;
            const bool keepMax = (((ll & k) != 0) == ((ll & d) != 0));
            const bool mineBig = (kx > other);
            kx = (keepMax == mineBig) ? kx : other;
        }
    }
    const unsigned sord = (unsigned)(kx >> 32);
    const unsigned su = (sord & 0x80000000u) ? (sord & 0x7FFFFFFFu) : ~sord;
    const float sval = __uint_as_float(su);
    const int sidx = 1023 - (int)(kx & 1023u);

    const float kc0 = kcont[b * 3 + 0], kc1 = kcont[b * 3 + 1], kc2 = kcont[b * 3 + 2];
    const float w0 = wbr[b * 3 + 0], w1 = wbr[b * 3 + 1], w2 = wbr[b * 3 + 2];

    const float p = __expf(sval - maxv) * invden;
    const float rr = (float)ll + 0.5f;
    const float g0 = sigm(12.f * (kc0 - rr));
    const float g1 = sigm(12.f * (kc1 - rr));
    const float g2 = sigm(12.f * (kc2 - rr));
    float s0 = p * g0, s1 = p * g1, s2 = p * g2;
#pragma unroll
    for (int d = 1; d < 16; d <<= 1) {
        s0 += sxrf(s0, d);
        s1 += sxrf(s1, d);
        s2 += sxrf(s2, d);
    }
    const float f0 = w0 / (s0 + 1e-8f);
    const float f1 = w1 / (s1 + 1e-8f);
    const float f2 = w2 / (s2 + 1e-8f);
    const float mycoef = p * (f0 * g0 + f1 * g1 + f2 * g2);

    // gather: 16 coalesced 1KB rows; rank-r coef/idx via v_readlane from lane r
    const unsigned short* hbase = h + (long long)b * (N_ * DIM_) + lane * 8;
    float acc[8] = {0.f, 0.f, 0.f, 0.f, 0.f, 0.f, 0.f, 0.f};
#pragma unroll
    for (int r = 0; r < TOPK; ++r) {
        const float c = __uint_as_float(
            (unsigned)__builtin_amdgcn_readlane((int)__float_as_uint(mycoef), r));
        const int   i = __builtin_amdgcn_readlane(sidx, r);
        const ushort4 a0 = *(const ushort4*)(hbase + (long long)i * DIM_);
        const ushort4 a1 = *(const ushort4*)(hbase + (long long)i * DIM_ + 4);
        acc[0] = fmaf(c, bf2f(a0.x), acc[0]);
        acc[1] = fmaf(c, bf2f(a0.y), acc[1]);
        acc[2] = fmaf(c, bf2f(a0.z), acc[2]);
        acc[3] = fmaf(c, bf2f(a0.w), acc[3]);
        acc[4] = fmaf(c, bf2f(a1.x), acc[4]);
        acc[5] = fmaf(c, bf2f(a1.y), acc[5]);
        acc[6] = fmaf(c, bf2f(a1.z), acc[6]);
        acc[7] = fmaf(c, bf2f(a1.w), acc[7]);
    }
    float* yp = y + (long long)row * DIM_ + lane * 8;
    *(float4*)(yp + 0) = make_float4(acc[0], acc[1], acc[2], acc[3]);
    *(float4*)(yp + 4) = make_float4(acc[4], acc[5], acc[6], acc[7]);
}

extern "C" void kernel_launch(void* const* d_in, const int* in_sizes, int n_in,
                              void* d_out, int out_size, void* d_ws, size_t ws_size,
                              hipStream_t stream) {
    const float* x     = (const float*)d_in[0];
    const float* fc1_w = (const float*)d_in[1];
    const float* fc1_b = (const float*)d_in[2];
    const float* fc2_w = (const float*)d_in[3];
    const float* fc2_b = (const float*)d_in[4];
    const float* k1_w  = (const float*)d_in[5];
    const float* k1_b  = (const float*)d_in[6];
    const float* k2_w  = (const float*)d_in[7];
    const float* k2_b  = (const float*)d_in[8];
    const float* w1_w  = (const float*)d_in[9];
    const float* w1_b  = (const float*)d_in[10];
    const float* w2_w  = (const float*)d_in[11];
    const float* w2_b  = (const float*)d_in[12];

    char* ws = (char*)d_ws;
    short* h1b    = (short*)(ws + 0);              // 33,554,432 (live fc1->fc2)
    float* simbuf = (float*)(ws + 0);              // 33,554,432 (reuse after fc2)
    short* xb     = (short*)(ws + 33554432);       // 8,388,608
    short* hb     = (short*)(ws + 67108864);       // 8,388,608
    short* w1b    = (short*)(ws + 75497472);       // 2,097,152
    short* w2b    = (short*)(ws + 77594624);       // 2,097,152
    float* ppart  = (float*)(ws + 79691776);       // 2,097,152 (256 blocks x 4 rowgroups x 512)
    float* kcont  = (float*)(ws + 81788928);       // 128
    float* wbr    = (float*)(ws + 81789056);       // 128

    float* y = (float*)d_out;

    // 0) fused prep: pooled partials + x->bf16 (blocks 0..255), weights->bf16 (256..511)
    prep_kernel<<<dim3(512), dim3(512), 0, stream>>>(x, ppart, xb, fc1_w, fc2_w, w1b, w2b);
    // 1) pooled reduce + head nets (wave-parallel matvec)
    pool_heads_kernel<<<dim3(B_), dim3(512), 0, stream>>>(ppart, k1_w, k1_b, k2_w, k2_b,
                                                          w1_w, w1_b, w2_w, w2_b, kcont, wbr);
    // 2) h1 = relu(x @ fc1_w^T + b1) -> bf16   M=8192 N=2048 K=512
    //    A/B: back to 128x128 2-barrier kernel (1024 blocks, 4/CU). gemm256 at NT=8 /
    //    1 block/CU never amortizes its prologue; R0->R3 arithmetic says this is ~2us faster.
    gemm_mfma<0, 128, 2><<<dim3(HID_ / 128, ROWS_ / 128, 1), dim3(256), 0, stream>>>(
        xb, w1b, fc1_b, nullptr, h1b, ROWS_, HID_, DIM_, DIM_, DIM_, 0, 0, 0);
    // 3) h = h1 @ fc2_w^T + b2 -> bf16 direct  M=8192 N=512 K=2048
    //    REVERTED to BN=64 (512 blocks, 2/CU: keeps implicit drain overlap; R8: BN=128 +5us)
    gemm_mfma<1, 64, 2><<<dim3(DIM_ / 64, ROWS_ / 128, 1), dim3(256), 0, stream>>>(
        h1b, w2b, fc2_b, nullptr, hb, ROWS_, DIM_, HID_, HID_, HID_, 0, 0, 0);
    // 4) sim[b] = hb[b] @ hb[b]^T -> fp32      M=N=1024 K=512, batch 8 (batch-XCD pinned)
    gemm_mfma<2, 128, 1><<<dim3(N_ / 128, N_ / 128, B_), dim3(256), 0, stream>>>(
        hb, hb, nullptr, simbuf, nullptr, N_, N_, DIM_, DIM_, DIM_,
        (long long)N_ * DIM_, (long long)N_ * DIM_, (long long)N_ * N_);
    // 5) fused per-row top-16 + aggregate (1 row/wave, R5-proven structure)
    topk_agg_kernel<<<dim3(ROWS_ / 4), dim3(256), 0, stream>>>(
        simbuf, kcont, wbr, (const unsigned short*)hb, y);
}

// Round 10
// 207.186 us; speedup vs baseline: 1.4126x; 1.0180x over previous
//
#include <hip/hip_runtime.h>
#include <math.h>

#define DIM_ 512
#define HID_ 2048
#define B_ 8
#define N_ 1024
#define ROWS_ 8192   // B_*N_
#define TOPK 16      // exact: gate at rank>=16 is <= e^-54 (k<12), contribution ~1e-20

typedef __attribute__((ext_vector_type(8))) short short8;
typedef __attribute__((ext_vector_type(16))) float float16v;
typedef __attribute__((ext_vector_type(4))) float float4v;

__device__ __forceinline__ float sigm(float x) { return 1.f / (1.f + __expf(-x)); }

__device__ __forceinline__ short f2bf(float f) {           // RNE fp32 -> bf16
    unsigned u = __float_as_uint(f);
    u += 0x7FFF + ((u >> 16) & 1);
    return (short)(u >> 16);
}

__device__ __forceinline__ float bf2f(unsigned short s) {
    return __uint_as_float((unsigned)s << 16);
}

__device__ __forceinline__ unsigned f2ord(float f) {       // monotone fp32 -> u32
    unsigned u = __float_as_uint(f);
    return (u & 0x80000000u) ? ~u : (u | 0x80000000u);
}

// ---- cross-lane helpers: xor1/xor2 on the VALU pipe (DPP quad_perm), rest LDS pipe ----
__device__ __forceinline__ unsigned dpp_xor1(unsigned v) {  // quad_perm [1,0,3,2]
    return (unsigned)__builtin_amdgcn_update_dpp(0, (int)v, 0xB1, 0xF, 0xF, true);
}
__device__ __forceinline__ unsigned dpp_xor2(unsigned v) {  // quad_perm [2,3,0,1]
    return (unsigned)__builtin_amdgcn_update_dpp(0, (int)v, 0x4E, 0xF, 0xF, true);
}
__device__ __forceinline__ unsigned sxr(unsigned v, int d) { // d folds to const after unroll
    if (d == 1) return dpp_xor1(v);
    if (d == 2) return dpp_xor2(v);
    return (unsigned)__shfl_xor((int)v, d);
}
__device__ __forceinline__ float sxrf(float v, int d) {
    return __uint_as_float(sxr(__float_as_uint(v), d));
}

__device__ __forceinline__ void gload16(const short* g, short* l) {
    __builtin_amdgcn_global_load_lds(
        (const __attribute__((address_space(1))) void*)g,
        (__attribute__((address_space(3))) void*)l, 16, 0, 0);
}

// ---------------- fused prep: pooled partials + x->bf16  |  weights->bf16 ----------------
__global__ __launch_bounds__(512)
void prep_kernel(const float* __restrict__ x, float* __restrict__ part, short* __restrict__ xb,
                 const float* __restrict__ w1, const float* __restrict__ w2,
                 short* __restrict__ o1, short* __restrict__ o2) {
    const int bx = blockIdx.x;
    if (bx < 256) {
        const int b = bx >> 5, chunk = bx & 31;
        const int cg = (threadIdx.x & 127) * 4;        // channel base (0..508)
        const int rg = threadIdx.x >> 7;               // row-group 0..3 (8 rows each)
        const long long rbase = (long long)b * N_ + chunk * 32 + rg * 8;
        const float* xp = x + rbase * DIM_ + cg;
        short* xo = xb + rbase * DIM_ + cg;
        float4 s = make_float4(0.f, 0.f, 0.f, 0.f);
#pragma unroll
        for (int n = 0; n < 8; ++n) {
            const float4 v = *(const float4*)(xp + (long long)n * DIM_);
            s.x += v.x; s.y += v.y; s.z += v.z; s.w += v.w;
            short4 o;
            o.x = f2bf(v.x); o.y = f2bf(v.y); o.z = f2bf(v.z); o.w = f2bf(v.w);
            *(short4*)(xo + (long long)n * DIM_) = o;
        }
        *(float4*)(part + ((long long)bx * 4 + rg) * DIM_ + cg) = s;
    } else {
        const int n4 = HID_ * DIM_ / 4;                // 262144 float4 per matrix
        int i = (bx - 256) * 2048 + threadIdx.x;
#pragma unroll
        for (int t = 0; t < 4; ++t, i += 512) {
            const float* in = (i < n4) ? w1 : w2;
            short* out = (i < n4) ? o1 : o2;
            const int j = (i < n4) ? i : (i - n4);
            const float4 v = *(const float4*)(in + (long long)j * 4);
            short4 o;
            o.x = f2bf(v.x); o.y = f2bf(v.y); o.z = f2bf(v.z); o.w = f2bf(v.w);
            *(short4*)(out + (long long)j * 4) = o;
        }
    }
}

// ---------------- pooled reduce + head nets (fused): k_cont (B,3), w (B,3) ----------------
__global__ __launch_bounds__(512)
void pool_heads_kernel(const float* __restrict__ part,
                       const float* __restrict__ k1w, const float* __restrict__ k1b,
                       const float* __restrict__ k2w, const float* __restrict__ k2b,
                       const float* __restrict__ w1w, const float* __restrict__ w1b,
                       const float* __restrict__ w2w, const float* __restrict__ w2b,
                       float* __restrict__ kcont, float* __restrict__ wbr) {
    const int b = blockIdx.x;
    const int t = threadIdx.x;                     // 512
    __shared__ float sp[DIM_];
    __shared__ float kh[128], wh[128];
    __shared__ float wraw[4];
    float s = 0.f;
    for (int g = 0; g < 128; ++g) s += part[((long long)b * 128 + g) * DIM_ + t];
    sp[t] = s * (1.f / 1024.f);
    __syncthreads();

    const int wv = t >> 6, l = t & 63;
    float sv[8];
    {
        const float4 a = *(const float4*)&sp[l * 8];
        const float4 c = *(const float4*)&sp[l * 8 + 4];
        sv[0] = a.x; sv[1] = a.y; sv[2] = a.z; sv[3] = a.w;
        sv[4] = c.x; sv[5] = c.y; sv[6] = c.z; sv[7] = c.w;
    }
#pragma unroll 4
    for (int i = 0; i < 16; ++i) {
        const int r = wv * 16 + i;
        const float4 k0 = *(const float4*)(k1w + (long long)r * DIM_ + l * 8);
        const float4 k1 = *(const float4*)(k1w + (long long)r * DIM_ + l * 8 + 4);
        const float4 q0 = *(const float4*)(w1w + (long long)r * DIM_ + l * 8);
        const float4 q1 = *(const float4*)(w1w + (long long)r * DIM_ + l * 8 + 4);
        float ak = sv[0] * k0.x;
        ak = fmaf(sv[1], k0.y, ak); ak = fmaf(sv[2], k0.z, ak); ak = fmaf(sv[3], k0.w, ak);
        ak = fmaf(sv[4], k1.x, ak); ak = fmaf(sv[5], k1.y, ak);
        ak = fmaf(sv[6], k1.z, ak); ak = fmaf(sv[7], k1.w, ak);
        float aw = sv[0] * q0.x;
        aw = fmaf(sv[1], q0.y, aw); aw = fmaf(sv[2], q0.z, aw); aw = fmaf(sv[3], q0.w, aw);
        aw = fmaf(sv[4], q1.x, aw); aw = fmaf(sv[5], q1.y, aw);
        aw = fmaf(sv[6], q1.z, aw); aw = fmaf(sv[7], q1.w, aw);
#pragma unroll
        for (int d = 32; d > 0; d >>= 1) {
            ak += __shfl_xor(ak, d);
            aw += __shfl_xor(aw, d);
        }
        if (l == 0) {
            kh[r] = fmaxf(ak + k1b[r], 0.f);
            wh[r] = fmaxf(aw + w1b[r], 0.f);
        }
    }
    __syncthreads();
    if (t < 3) {
        float rk = k2b[t], rw = w2b[t];
        for (int k = 0; k < 128; ++k) {
            rk = fmaf(kh[k], k2w[t * 128 + k], rk);
            rw = fmaf(wh[k], w2w[t * 128 + k], rw);
        }
        kcont[b * 3 + t] = 1.f + 11.f * sigm(rk);
        wraw[t] = rw;
    }
    __syncthreads();
    if (t == 0) {
        const float m = fmaxf(wraw[0], fmaxf(wraw[1], wraw[2]));
        const float e0 = __expf(wraw[0] - m), e1 = __expf(wraw[1] - m), e2 = __expf(wraw[2] - m);
        const float inv = 1.f / (e0 + e1 + e2);
        wbr[b * 3 + 0] = e0 * inv;
        wbr[b * 3 + 1] = e1 * inv;
        wbr[b * 3 + 2] = e2 * inv;
    }
}

// ---------------- bf16 MFMA NT GEMM, 32x32x16, 128xBN tile (GEMM2 + GEMM3) ----------------
// 2-barrier structure needs >=2 blocks/CU for implicit drain overlap (R8: BN=128 at
// 1 block/CU cost +5us despite halved A-streaming).
template<int OUTMODE, int BN, int SWZ>
__global__ __launch_bounds__(256)
void gemm_mfma(const short* __restrict__ A, const short* __restrict__ Bm,
               const float* __restrict__ bias,
               float* __restrict__ outF, short* __restrict__ outB,
               int M, int N, int K, int lda, int ldb,
               long long sA, long long sB, long long sC) {
    constexpr int NJ = BN / 64;             // j-frags per wave (2 or 1)
    int bz, mi, ni;
    if (SWZ == 1) {
        const int id = blockIdx.x + gridDim.x * (blockIdx.y + gridDim.y * blockIdx.z);
        bz = id % gridDim.z;
        const int r = id / gridDim.z;
        ni = r % gridDim.x;
        mi = r / gridDim.x;
    } else {
        const int id = blockIdx.x + gridDim.x * blockIdx.y;
        const int numM = gridDim.y;
        const int mg = numM >> 3;           // m-tiles per batch-eighth
        bz = blockIdx.z;
        mi = (id & 7) * mg + (id >> 3) % mg;
        ni = id / numM;
    }
    A  += (long long)bz * sA;
    Bm += (long long)bz * sB;

    __shared__ short As[128 * 64];
    __shared__ short Bs[BN * 64];

    const int tid = threadIdx.x;
    const int lane = tid & 63;
    const int wv = tid >> 6;                // 0..3
    const int m0 = mi * 128;
    const int n0 = ni * BN;

    const int lrow = lane >> 3;             // 0..7
    const int cg = (lane & 7) ^ lrow;       // XOR swizzle

    const int ml = (wv & 1) * 64;
    const int nl = (wv >> 1) * (BN / 2);    // BN=128 -> 64, BN=64 -> 32
    const int fr = lane & 31;               // fragment row/col (m or n)
    const int khh = lane >> 5;              // k-half 0..1

    float16v acc[2][NJ];
#pragma unroll
    for (int i = 0; i < 2; ++i)
#pragma unroll
        for (int j = 0; j < NJ; ++j)
#pragma unroll
            for (int r = 0; r < 16; ++r) acc[i][j][r] = 0.f;

    for (int k0 = 0; k0 < K; k0 += 64) {
        __syncthreads();
#pragma unroll
        for (int i = 0; i < 4; ++i) {
            const int rloc = wv * 32 + i * 8 + lrow;
            gload16(A + (long long)(m0 + rloc) * lda + (k0 + cg * 8),
                    &As[(wv * 32 + i * 8) * 64]);
        }
#pragma unroll
        for (int i = 0; i < BN / 32; ++i) {
            const int rloc = wv * (BN / 4) + i * 8 + lrow;
            gload16(Bm + (long long)(n0 + rloc) * ldb + (k0 + cg * 8),
                    &Bs[(wv * (BN / 4) + i * 8) * 64]);
        }
        __syncthreads();
#pragma unroll
        for (int c = 0; c < 4; ++c) {           // 4 ksteps of K=16
            const int ch = c * 2 + khh;         // 8-elem chunk index
            short8 af[2], bfr[NJ];
#pragma unroll
            for (int i = 0; i < 2; ++i) {
                const int m = ml + i * 32 + fr;
                af[i] = *(const short8*)&As[m * 64 + ((ch ^ (m & 7)) * 8)];
            }
#pragma unroll
            for (int j = 0; j < NJ; ++j) {
                const int n = nl + j * 32 + fr;
                bfr[j] = *(const short8*)&Bs[n * 64 + ((ch ^ (n & 7)) * 8)];
            }
#pragma unroll
            for (int i = 0; i < 2; ++i)
#pragma unroll
                for (int j = 0; j < NJ; ++j)
                    acc[i][j] = __builtin_amdgcn_mfma_f32_32x32x16_bf16(
                        af[i], bfr[j], acc[i][j], 0, 0, 0);
        }
    }

    const long long outOfs = (long long)bz * sC;
#pragma unroll
    for (int i = 0; i < 2; ++i) {
#pragma unroll
        for (int j = 0; j < NJ; ++j) {
            const int ng = n0 + nl + j * 32 + fr;
            float bv = 0.f;
            if (OUTMODE != 2) bv = bias[ng];
#pragma unroll
            for (int r = 0; r < 16; ++r) {
                const int mg2 = m0 + ml + i * 32 + (r & 3) + 8 * (r >> 2) + 4 * khh;
                float v = acc[i][j][r] + bv;
                if (OUTMODE == 0) v = fmaxf(v, 0.f);
                const long long idx = outOfs + (long long)mg2 * N + ng;
                if (OUTMODE == 2) outF[idx] = v;
                else              outB[idx] = f2bf(v);
            }
        }
    }
}

// ---------------- bf16 MFMA NT GEMM, 256x256 8-phase deep-pipelined (GEMM1) -------
// 8 waves (2M x 4N), per-wave 128x64 out, MFMA 16x16x32, BK=64, LDS 128 KiB dbuf.
// Counted vmcnt {6,6,-,4} steady, epilogue {2,0,-,-}; never vmcnt(0) in main loop.
// R9 A/B: equal to the 128-tile kernel at this shape (K=512); kept as best-measured (R5).
template<int OUTMODE, bool BATCH>
__global__ __launch_bounds__(512, 2)
void gemm256(const short* __restrict__ A, const short* __restrict__ Bm,
             const float* __restrict__ bias, float* __restrict__ outF,
             short* __restrict__ outB, int M, int N, int K, int lda, int ldb,
             int mTiles, long long sA, long long sB, long long sC) {
    __shared__ short As[2][256 * 64];
    __shared__ short Bs[2][256 * 64];

    const int tid = threadIdx.x;
    const int lane = tid & 63;
    const int wv = tid >> 6;           // 0..7
    const int l15 = lane & 15;
    const int kq = lane >> 4;          // 0..3
    const int lr = lane >> 3;          // 0..7 stripe-row
    const int cg = (lane & 7) ^ lr;    // pre-swizzled source chunk

    const int id = blockIdx.x;
    const int xcd = id & 7;            // batch / m-group -> XCD pinned
    const int r = id >> 3;
    int mi, ni;
    const short* Ag = A;
    const short* Bg = Bm;
    long long cOfs = 0;
    if (BATCH) {
        mi = r % mTiles; ni = r / mTiles;
        Ag += (long long)xcd * sA; Bg += (long long)xcd * sB; cOfs = (long long)xcd * sC;
    } else {
        const int mg = mTiles >> 3;    // m-tiles per XCD chunk
        mi = xcd * mg + r % mg; ni = r / mg;
    }
    const int m0 = mi * 256, n0 = ni * 256;
    const int wm = wv >> 2, wn = wv & 3;

    float4v acc[8][4];
#pragma unroll
    for (int i = 0; i < 8; ++i)
#pragma unroll
        for (int j = 0; j < 4; ++j)
#pragma unroll
            for (int q = 0; q < 4; ++q) acc[i][j][q] = 0.f;

    const int sB1 = (wv & 3) + (wv >> 2) * 8;

    auto stA = [&](int bf, int s, int k0) {
        gload16(Ag + (long long)(m0 + s * 8 + lr) * lda + (k0 + cg * 8), &As[bf][s * 8 * 64]);
    };
    auto stB = [&](int bf, int s, int k0) {
        gload16(Bg + (long long)(n0 + s * 8 + lr) * ldb + (k0 + cg * 8), &Bs[bf][s * 8 * 64]);
    };
    auto unit0 = [&](int bf, int k0) {
        stA(bf, wv, k0); stA(bf, 16 + wv, k0);
        stB(bf, sB1, k0); stB(bf, 16 + sB1, k0);
    };
    auto unit1 = [&](int bf, int k0) { stA(bf, 8 + wv, k0); stA(bf, 24 + wv, k0); };
    auto unit2 = [&](int bf, int k0) { stB(bf, 4 + sB1, k0); stB(bf, 20 + sB1, k0); };

    auto tile_body = [&](int bf, int k1, bool stage) {
#pragma unroll
        for (int p = 0; p < 4; ++p) {
            const int mq = p & 1, nq = p >> 1;
            short8 af[4][2], bfr[2][2];
#pragma unroll
            for (int f = 0; f < 4; ++f) {
                const int rA = wm * 128 + mq * 64 + f * 16 + l15;
                const int ro = rA * 64, sw = rA & 7;
#pragma unroll
                for (int ks = 0; ks < 2; ++ks)
                    af[f][ks] = *(const short8*)&As[bf][ro + (((ks * 4 + kq) ^ sw) * 8)];
            }
#pragma unroll
            for (int g = 0; g < 2; ++g) {
                const int rB = wn * 64 + nq * 32 + g * 16 + l15;
                const int ro = rB * 64, sw = rB & 7;
#pragma unroll
                for (int ks = 0; ks < 2; ++ks)
                    bfr[g][ks] = *(const short8*)&Bs[bf][ro + (((ks * 4 + kq) ^ sw) * 8)];
            }
            if (stage) {
                if (p == 0) unit0(bf ^ 1, k1);
                else if (p == 1) unit1(bf ^ 1, k1);
                else if (p == 2) unit2(bf ^ 1, k1);
                if (p == 0 || p == 1) asm volatile("s_waitcnt vmcnt(6)" ::: "memory");
                else if (p == 3)      asm volatile("s_waitcnt vmcnt(4)" ::: "memory");
            } else {
                if (p == 0)      asm volatile("s_waitcnt vmcnt(2)" ::: "memory");
                else if (p == 1) asm volatile("s_waitcnt vmcnt(0)" ::: "memory");
            }
            __builtin_amdgcn_s_barrier();
            asm volatile("s_waitcnt lgkmcnt(0)" ::: "memory");
            __builtin_amdgcn_sched_barrier(0);          // rule #18: pin MFMA after the wait
            __builtin_amdgcn_s_setprio(1);
#pragma unroll
            for (int f = 0; f < 4; ++f)
#pragma unroll
                for (int g = 0; g < 2; ++g)
#pragma unroll
                    for (int ks = 0; ks < 2; ++ks)
                        acc[mq * 4 + f][nq * 2 + g] = __builtin_amdgcn_mfma_f32_16x16x32_bf16(
                            af[f][ks], bfr[g][ks], acc[mq * 4 + f][nq * 2 + g], 0, 0, 0);
            __builtin_amdgcn_s_setprio(0);
            if (stage || p < 3) __builtin_amdgcn_s_barrier();
        }
    };

    const int NT = K >> 6;             // >= 2 for all uses here
    // prologue: stage tile 0 fully (unit order fixed for vmcnt accounting)
    unit0(0, 0);
    __builtin_amdgcn_sched_barrier(0);
    unit1(0, 0);
    __builtin_amdgcn_sched_barrier(0);
    unit2(0, 0);
    asm volatile("s_waitcnt vmcnt(4)" ::: "memory");   // U0 landed; U1,U2 in flight
    __builtin_amdgcn_s_barrier();

    for (int t = 0; t < NT - 1; ++t)
        tile_body(t & 1, (t + 1) << 6, true);
    tile_body((NT - 1) & 1, 0, false);                 // epilogue tile, drains 2->0

    // C-write: col = lane&15, row = (lane>>4)*4 + reg
#pragma unroll
    for (int mf = 0; mf < 8; ++mf) {
#pragma unroll
        for (int nf = 0; nf < 4; ++nf) {
            const int ng = n0 + wn * 64 + nf * 16 + l15;
            float bv = 0.f;
            if (OUTMODE != 2) bv = bias[ng];
            const int mb = m0 + wm * 128 + mf * 16 + kq * 4;
#pragma unroll
            for (int q = 0; q < 4; ++q) {
                float v = acc[mf][nf][q] + bv;
                if (OUTMODE == 0) v = fmaxf(v, 0.f);
                const long long idx = cOfs + (long long)(mb + q) * N + ng;
                if (OUTMODE == 2) outF[idx] = v;
                else              outB[idx] = f2bf(v);
            }
        }
    }
}

// ---------------- fused per-row top-16 + aggregate, ONE row per wave (R5-proven) ----------
// 22-bit-key bitonic sort + 6 merge rounds (xor1/2 on DPP), exact fp32 re-rank in
// 16-lane groups, readlane gather. VGPR=48, no spill.
__global__ __launch_bounds__(256)
void topk_agg_kernel(const float* __restrict__ sim,
                     const float* __restrict__ kcont, const float* __restrict__ wbr,
                     const unsigned short* __restrict__ h, float* __restrict__ y) {
    const int wv = threadIdx.x >> 6;
    const int lane = threadIdx.x & 63;
    const int ll = lane & 15;
    const int id = blockIdx.x;                    // 2048
    const int b = id & 7;                         // batch -> XCD pinned
    const int row = b * N_ + (id >> 3) * 4 + wv;  // 1024 rows per batch
    const float* srow = sim + (long long)row * N_;

    const int base = lane * 16;
    float f[16];
#pragma unroll
    for (int q = 0; q < 4; ++q) {
        const float4 v = *(const float4*)(srow + base + q * 4);
        f[q * 4 + 0] = v.x; f[q * 4 + 1] = v.y; f[q * 4 + 2] = v.z; f[q * 4 + 3] = v.w;
    }

    // row max
    float m = f[0];
#pragma unroll
    for (int j = 1; j < 16; ++j) m = fmaxf(m, f[j]);
#pragma unroll
    for (int d = 32; d > 0; d >>= 1) m = fmaxf(m, sxrf(m, d));
    const float maxv = m;

    // softmax denominator
    float so = 0.f;
#pragma unroll
    for (int j = 0; j < 16; ++j) so += __expf(f[j] - maxv);
#pragma unroll
    for (int d = 32; d > 0; d >>= 1) so += sxrf(so, d);
    const float invden = 1.f / so;

    // ---- Phase A: u32 keys (top-22 float bits | index), lane-local bitonic sort desc ----
    unsigned key[16];
#pragma unroll
    for (int j = 0; j < 16; ++j)
        key[j] = (f2ord(f[j]) & 0xFFFFFC00u) | (unsigned)(1023 - (base + j));

#pragma unroll
    for (int k = 2; k <= 16; k <<= 1) {
#pragma unroll
        for (int j = k >> 1; j > 0; j >>= 1) {
#pragma unroll
            for (int i = 0; i < 16; ++i) {
                const int l = i ^ j;
                if (l > i) {
                    const bool desc = ((i & k) == 0);
                    const unsigned a = key[i], bk = key[l];
                    const unsigned hi = (a > bk) ? a : bk;
                    const unsigned lo = (a > bk) ? bk : a;
                    key[i] = desc ? hi : lo;
                    key[l] = desc ? lo : hi;
                }
            }
        }
    }

    // 6 merge rounds -> every lane holds global sorted top-16 (desc) in key[0..15]
#pragma unroll
    for (int d = 1; d < 64; d <<= 1) {
        unsigned o[16];
#pragma unroll
        for (int i = 0; i < 16; ++i) o[i] = sxr(key[15 - i], d);
#pragma unroll
        for (int i = 0; i < 16; ++i) key[i] = (key[i] > o[i]) ? key[i] : o[i];
#pragma unroll
        for (int j = 8; j > 0; j >>= 1) {
#pragma unroll
            for (int i = 0; i < 16; ++i) {
                if ((i & j) == 0) {
                    const unsigned a = key[i], bk = key[i | j];
                    key[i]     = (a > bk) ? a : bk;
                    key[i | j] = (a > bk) ? bk : a;
                }
            }
        }
    }

    // ---- Phase B: 4 identical 16-lane groups resolve exact fp32 order of top-16 ----
    unsigned k32 = 0;
#pragma unroll
    for (int j = 0; j < 16; ++j) k32 = (ll == j) ? key[j] : k32;
    const int myidx = 1023 - (int)(k32 & 1023u);
    const float myval = srow[myidx];                 // L1-hot exact fp32

    unsigned long long kx = ((unsigned long long)f2ord(myval) << 32)
                          | (unsigned)(1023 - myidx);
#pragma unroll
    for (int k = 2; k <= 16; k <<= 1) {
#pragma unroll
        for (int d = k >> 1; d > 0; d >>= 1) {       // d<=8: stays in 16-lane group
            const unsigned olo = sxr((unsigned)kx, d);
            const unsigned ohi = sxr((unsigned)(kx >> 32), d);
            const unsigned long long other = ((unsigned long long)ohi << 32) | olo;
            const bool keepMax = (((ll & k) != 0) == ((ll & d) != 0));
            const bool mineBig = (kx > other);
            kx = (keepMax == mineBig) ? kx : other;
        }
    }
    const unsigned sord = (unsigned)(kx >> 32);
    const unsigned su = (sord & 0x80000000u) ? (sord & 0x7FFFFFFFu) : ~sord;
    const float sval = __uint_as_float(su);
    const int sidx = 1023 - (int)(kx & 1023u);

    const float kc0 = kcont[b * 3 + 0], kc1 = kcont[b * 3 + 1], kc2 = kcont[b * 3 + 2];
    const float w0 = wbr[b * 3 + 0], w1 = wbr[b * 3 + 1], w2 = wbr[b * 3 + 2];

    const float p = __expf(sval - maxv) * invden;
    const float rr = (float)ll + 0.5f;
    const float g0 = sigm(12.f * (kc0 - rr));
    const float g1 = sigm(12.f * (kc1 - rr));
    const float g2 = sigm(12.f * (kc2 - rr));
    float s0 = p * g0, s1 = p * g1, s2 = p * g2;
#pragma unroll
    for (int d = 1; d < 16; d <<= 1) {
        s0 += sxrf(s0, d);
        s1 += sxrf(s1, d);
        s2 += sxrf(s2, d);
    }
    const float f0 = w0 / (s0 + 1e-8f);
    const float f1 = w1 / (s1 + 1e-8f);
    const float f2 = w2 / (s2 + 1e-8f);
    const float mycoef = p * (f0 * g0 + f1 * g1 + f2 * g2);

    // gather: 16 coalesced 1KB rows; rank-r coef/idx via v_readlane from lane r
    const unsigned short* hbase = h + (long long)b * (N_ * DIM_) + lane * 8;
    float acc[8] = {0.f, 0.f, 0.f, 0.f, 0.f, 0.f, 0.f, 0.f};
#pragma unroll
    for (int r = 0; r < TOPK; ++r) {
        const float c = __uint_as_float(
            (unsigned)__builtin_amdgcn_readlane((int)__float_as_uint(mycoef), r));
        const int   i = __builtin_amdgcn_readlane(sidx, r);
        const ushort4 a0 = *(const ushort4*)(hbase + (long long)i * DIM_);
        const ushort4 a1 = *(const ushort4*)(hbase + (long long)i * DIM_ + 4);
        acc[0] = fmaf(c, bf2f(a0.x), acc[0]);
        acc[1] = fmaf(c, bf2f(a0.y), acc[1]);
        acc[2] = fmaf(c, bf2f(a0.z), acc[2]);
        acc[3] = fmaf(c, bf2f(a0.w), acc[3]);
        acc[4] = fmaf(c, bf2f(a1.x), acc[4]);
        acc[5] = fmaf(c, bf2f(a1.y), acc[5]);
        acc[6] = fmaf(c, bf2f(a1.z), acc[6]);
        acc[7] = fmaf(c, bf2f(a1.w), acc[7]);
    }
    float* yp = y + (long long)row * DIM_ + lane * 8;
    *(float4*)(yp + 0) = make_float4(acc[0], acc[1], acc[2], acc[3]);
    *(float4*)(yp + 4) = make_float4(acc[4], acc[5], acc[6], acc[7]);
}

extern "C" void kernel_launch(void* const* d_in, const int* in_sizes, int n_in,
                              void* d_out, int out_size, void* d_ws, size_t ws_size,
                              hipStream_t stream) {
    const float* x     = (const float*)d_in[0];
    const float* fc1_w = (const float*)d_in[1];
    const float* fc1_b = (const float*)d_in[2];
    const float* fc2_w = (const float*)d_in[3];
    const float* fc2_b = (const float*)d_in[4];
    const float* k1_w  = (const float*)d_in[5];
    const float* k1_b  = (const float*)d_in[6];
    const float* k2_w  = (const float*)d_in[7];
    const float* k2_b  = (const float*)d_in[8];
    const float* w1_w  = (const float*)d_in[9];
    const float* w1_b  = (const float*)d_in[10];
    const float* w2_w  = (const float*)d_in[11];
    const float* w2_b  = (const float*)d_in[12];

    char* ws = (char*)d_ws;
    short* h1b    = (short*)(ws + 0);              // 33,554,432 (live fc1->fc2)
    float* simbuf = (float*)(ws + 0);              // 33,554,432 (reuse after fc2)
    short* xb     = (short*)(ws + 33554432);       // 8,388,608
    short* hb     = (short*)(ws + 67108864);       // 8,388,608
    short* w1b    = (short*)(ws + 75497472);       // 2,097,152
    short* w2b    = (short*)(ws + 77594624);       // 2,097,152
    float* ppart  = (float*)(ws + 79691776);       // 2,097,152 (256 blocks x 4 rowgroups x 512)
    float* kcont  = (float*)(ws + 81788928);       // 128
    float* wbr    = (float*)(ws + 81789056);       // 128

    float* y = (float*)d_out;

    // 0) fused prep: pooled partials + x->bf16 (blocks 0..255), weights->bf16 (256..511)
    prep_kernel<<<dim3(512), dim3(512), 0, stream>>>(x, ppart, xb, fc1_w, fc2_w, w1b, w2b);
    // 1) pooled reduce + head nets (wave-parallel matvec)
    pool_heads_kernel<<<dim3(B_), dim3(512), 0, stream>>>(ppart, k1_w, k1_b, k2_w, k2_b,
                                                          w1_w, w1_b, w2_w, w2_b, kcont, wbr);
    // 2) h1 = relu(x @ fc1_w^T + b1) -> bf16   M=8192 N=2048 K=512
    //    256x256 8-phase: 32x8 = 256 blocks, 1/CU, m-tiles XCD-pinned (R5 best-measured)
    gemm256<0, false><<<dim3(256), dim3(512), 0, stream>>>(
        xb, w1b, fc1_b, nullptr, h1b, ROWS_, HID_, DIM_, DIM_, DIM_, 32, 0, 0, 0);
    // 3) h = h1 @ fc2_w^T + b2 -> bf16 direct  M=8192 N=512 K=2048 (BN=64, 512 blocks, 2/CU)
    gemm_mfma<1, 64, 2><<<dim3(DIM_ / 64, ROWS_ / 128, 1), dim3(256), 0, stream>>>(
        h1b, w2b, fc2_b, nullptr, hb, ROWS_, DIM_, HID_, HID_, HID_, 0, 0, 0);
    // 4) sim[b] = hb[b] @ hb[b]^T -> fp32      M=N=1024 K=512, batch 8 (batch-XCD pinned)
    gemm_mfma<2, 128, 1><<<dim3(N_ / 128, N_ / 128, B_), dim3(256), 0, stream>>>(
        hb, hb, nullptr, simbuf, nullptr, N_, N_, DIM_, DIM_, DIM_,
        (long long)N_ * DIM_, (long long)N_ * DIM_, (long long)N_ * N_);
    // 5) fused per-row top-16 + aggregate (1 row/wave, R5-proven structure)
    topk_agg_kernel<<<dim3(ROWS_ / 4), dim3(256), 0, stream>>>(
        simbuf, kcont, wbr, (const unsigned short*)hb, y);
}